// Round 1
// baseline (627.139 us; speedup 1.0000x reference)
//
#include <hip/hip_runtime.h>
#include <cstdint>
#include <cstddef>

#define T_TOK 2048
#define H_DIM 2048
#define S_LEN 1024
#define HD 128
#define NH 16
#define NKV 4
#define QKV_O 3072
#define MM 512
#define EPS 1e-6f
#define ATT_SCALE 0.08838834764831845f  // 128^-0.5

typedef __bf16 bf16x8 __attribute__((ext_vector_type(8)));
typedef __bf16 bf16x4 __attribute__((ext_vector_type(4)));
typedef float  f32x4  __attribute__((ext_vector_type(4)));

__device__ __forceinline__ __bf16 f2bf(float f) {
  unsigned u = __builtin_bit_cast(unsigned, f);
  u += 0x7fffu + ((u >> 16) & 1u);           // RNE; inputs are finite
  unsigned short h = (unsigned short)(u >> 16);
  return __builtin_bit_cast(__bf16, h);
}
__device__ __forceinline__ __bf16 us2bf(unsigned short v) {
  return __builtin_bit_cast(__bf16, v);
}
__device__ __forceinline__ f32x4 fzero4() {
  f32x4 z; z[0] = 0.f; z[1] = 0.f; z[2] = 0.f; z[3] = 0.f; return z;
}

// ---------------------------------------------------------------------------
// RMSNorm over H=2048, fp32 in -> bf16 out. One block (256 thr) per token.
// ---------------------------------------------------------------------------
__global__ __launch_bounds__(256) void rmsnorm_k(const float* __restrict__ X,
                                                 const float* __restrict__ W,
                                                 __bf16* __restrict__ Y) {
  int t = blockIdx.x;
  int tid = threadIdx.x, lane = tid & 63, wid = tid >> 6;
  const float4* row = (const float4*)(X + (size_t)t * H_DIM);
  float4 v0 = row[tid], v1 = row[tid + 256];
  float ss = v0.x*v0.x + v0.y*v0.y + v0.z*v0.z + v0.w*v0.w
           + v1.x*v1.x + v1.y*v1.y + v1.z*v1.z + v1.w*v1.w;
  #pragma unroll
  for (int m = 1; m <= 32; m <<= 1) ss += __shfl_xor(ss, m, 64);
  __shared__ float red[4];
  if (lane == 0) red[wid] = ss;
  __syncthreads();
  float tot = red[0] + red[1] + red[2] + red[3];
  float sc = rsqrtf(tot * (1.f / H_DIM) + EPS);
  const float4* wp = (const float4*)W;
  float4 w0 = wp[tid], w1 = wp[tid + 256];
  bf16x4 o;
  o[0] = f2bf(v0.x*w0.x*sc); o[1] = f2bf(v0.y*w0.y*sc);
  o[2] = f2bf(v0.z*w0.z*sc); o[3] = f2bf(v0.w*w0.w*sc);
  *(bf16x4*)&Y[(size_t)t*H_DIM + tid*4] = o;
  o[0] = f2bf(v1.x*w1.x*sc); o[1] = f2bf(v1.y*w1.y*sc);
  o[2] = f2bf(v1.z*w1.z*sc); o[3] = f2bf(v1.w*w1.w*sc);
  *(bf16x4*)&Y[(size_t)t*H_DIM + 1024 + tid*4] = o;
}

// ---------------------------------------------------------------------------
// NT GEMM: C[M x N] = A(bf16, M x K row-major) * B(f32, N x K row-major)^T
// B is converted f32->bf16 while staging into LDS (weights stay fp32 in HBM).
// Tile 128x128, BK=64, 4 waves of 64x64, mfma 16x16x32 bf16.
// MODE 0: C fp32 plain store (ldc=N)
// MODE 1: C fp32 = acc + resid (ldc=2048)
// MODE 2: expert down-proj: grid.z=expert, gathered scatter:
//         atomicAdd(C[list[slot]*2048 + col], acc * wsl[slot])
// ---------------------------------------------------------------------------
template<int MODE>
__global__ __launch_bounds__(256) void gemm_nt(
    const __bf16* __restrict__ A, const float* __restrict__ B,
    const float* __restrict__ B2, float* __restrict__ C,
    const float* __restrict__ resid, const int* __restrict__ list,
    const float* __restrict__ wsl, const int* __restrict__ cnt,
    int N, int K) {
  int e  = (MODE == 2) ? (int)blockIdx.z : 0;
  int ne = (MODE == 2) ? ((e == 8) ? T_TOK : cnt[e]) : T_TOK;
  int m0 = blockIdx.y * 128;
  if (MODE == 2 && m0 >= ne) return;
  int n0 = blockIdx.x * 128;
  const __bf16* Ab = A;
  const float*  Bb = B;
  if (MODE == 2) {
    Ab = A + (size_t)e * T_TOK * MM;                 // he rows for this expert
    Bb = (e < 8) ? B + (size_t)e * H_DIM * MM : B2;  // we_down[e] or ws_down
  }
  __shared__ __bf16 sA[128 * 72];
  __shared__ __bf16 sB[128 * 72];
  f32x4 acc[4][4];
  #pragma unroll
  for (int i = 0; i < 4; i++)
    #pragma unroll
    for (int j = 0; j < 4; j++) acc[i][j] = fzero4();

  int tid = threadIdx.x, lane = tid & 63, wid = tid >> 6;
  int quad = lane >> 4, l16 = lane & 15;
  int wm = wid & 1, wn = wid >> 1;

  for (int k0 = 0; k0 < K; k0 += 64) {
    __syncthreads();
    #pragma unroll
    for (int i = 0; i < 4; i++) {          // A: 128 rows x 64 cols bf16
      int c = tid + 256 * i;
      int row = c >> 3, cc = c & 7;
      *(uint4*)&sA[row * 72 + cc * 8] =
          *((const uint4*)(Ab + (size_t)(m0 + row) * K + k0) + cc);
    }
    #pragma unroll
    for (int i = 0; i < 8; i++) {          // B: 128 rows x 64 cols f32->bf16
      int c = tid + 256 * i;
      int row = c >> 4, cc = c & 15;
      float4 f = *((const float4*)(Bb + (size_t)(n0 + row) * K + k0) + cc);
      bf16x4 h;
      h[0] = f2bf(f.x); h[1] = f2bf(f.y); h[2] = f2bf(f.z); h[3] = f2bf(f.w);
      *(bf16x4*)&sB[row * 72 + cc * 4] = h;
    }
    __syncthreads();
    #pragma unroll
    for (int ks = 0; ks < 64; ks += 32) {
      bf16x8 aF[4], bF[4];
      #pragma unroll
      for (int mt = 0; mt < 4; mt++)
        aF[mt] = *(const bf16x8*)&sA[(wm*64 + mt*16 + l16) * 72 + ks + quad*8];
      #pragma unroll
      for (int nt = 0; nt < 4; nt++)
        bF[nt] = *(const bf16x8*)&sB[(wn*64 + nt*16 + l16) * 72 + ks + quad*8];
      #pragma unroll
      for (int mt = 0; mt < 4; mt++)
        #pragma unroll
        for (int nt = 0; nt < 4; nt++)
          acc[mt][nt] = __builtin_amdgcn_mfma_f32_16x16x32_bf16(
              aF[mt], bF[nt], acc[mt][nt], 0, 0, 0);
    }
  }
  // Epilogue. C-layout: row = quad*4+reg, col = lane&15 (m89-verified).
  #pragma unroll
  for (int mt = 0; mt < 4; mt++) {
    #pragma unroll
    for (int nt = 0; nt < 4; nt++) {
      #pragma unroll
      for (int r = 0; r < 4; r++) {
        int row_l = wm*64 + mt*16 + quad*4 + r;
        int col_l = wn*64 + nt*16 + l16;
        int grow = m0 + row_l, gcol = n0 + col_l;
        float val = acc[mt][nt][r];
        if (MODE == 0) {
          C[(size_t)grow * N + gcol] = val;
        } else if (MODE == 1) {
          C[(size_t)grow * H_DIM + gcol] = val + resid[(size_t)grow * H_DIM + gcol];
        } else {
          if (grow < ne) {
            int tk  = list[e * T_TOK + grow];
            float w = wsl[e * T_TOK + grow];
            atomicAdd(&C[(size_t)tk * H_DIM + gcol], val * w);
          }
        }
      }
    }
  }
}

// ---------------------------------------------------------------------------
// Per (token, head): q/k RMSNorm (HD=128) + RoPE, v passthrough; fp32->bf16.
// Block = 64 threads; lane d holds elements d and d+64 (rotate_half pairing).
// ---------------------------------------------------------------------------
__global__ __launch_bounds__(64) void rope_k(
    const float* __restrict__ qkv, const float* __restrict__ qlw,
    const float* __restrict__ klw, const float* __restrict__ cosp,
    const float* __restrict__ sinp, __bf16* __restrict__ qb,
    __bf16* __restrict__ kb, __bf16* __restrict__ vb) {
  int bid = blockIdx.x;
  int head = bid % 24;
  int t = bid / 24;
  int b = t >> 10, s = t & 1023;
  int d = threadIdx.x;
  const float* src = qkv + (size_t)t * QKV_O + head * HD;
  float x1 = src[d], x2 = src[d + 64];
  if (head < 20) {
    float ssq = x1*x1 + x2*x2;
    #pragma unroll
    for (int m = 1; m <= 32; m <<= 1) ssq += __shfl_xor(ssq, m, 64);
    float sc = rsqrtf(ssq * (1.f / HD) + EPS);
    const float* w = (head < 16) ? qlw : klw;
    x1 = x1 * sc * w[d];
    x2 = x2 * sc * w[d + 64];
    size_t cb = (size_t)t * HD;
    float c1 = cosp[cb + d], s1 = sinp[cb + d];
    float c2 = cosp[cb + d + 64], s2 = sinp[cb + d + 64];
    float o1 = x1 * c1 - x2 * s1;   // rotate_half: first half gets -x2
    float o2 = x2 * c2 + x1 * s2;
    if (head < 16) {
      __bf16* dst = qb + (((size_t)(b * NH + head)) * S_LEN + s) * HD;
      dst[d] = f2bf(o1); dst[d + 64] = f2bf(o2);
    } else {
      int kv = head - 16;
      __bf16* dst = kb + (((size_t)(b * NKV + kv)) * S_LEN + s) * HD;
      dst[d] = f2bf(o1); dst[d + 64] = f2bf(o2);
    }
  } else {
    int kv = head - 20;
    __bf16* dst = vb + (((size_t)(b * NKV + kv)) * S_LEN + s) * HD;
    dst[d] = f2bf(x1); dst[d + 64] = f2bf(x2);
  }
}

// ---------------------------------------------------------------------------
// Flash attention (no mask). Block = 256 thr (4 waves), 64-row Q tile,
// K/V tiles of 64. Wave w owns Q rows [16w,16w+16). P does C->A layout
// round-trip through LDS (m120 pattern).
// ---------------------------------------------------------------------------
__global__ __launch_bounds__(256) void flash_k(
    const __bf16* __restrict__ qb, const __bf16* __restrict__ kb,
    const __bf16* __restrict__ vb, __bf16* __restrict__ outb) {
  int qt = blockIdx.x, bh = blockIdx.y;
  int b = bh >> 4, h = bh & 15, kv = h >> 2;
  int tid = threadIdx.x, lane = tid & 63, wid = tid >> 6;
  int quad = lane >> 4, l16 = lane & 15;
  __shared__ __bf16 sQ[64 * 136];
  __shared__ __bf16 sK[64 * 136];
  __shared__ __bf16 sVt[128 * 72];
  __shared__ __bf16 sP[64 * 72];

  const __bf16* qsrc = qb + (((size_t)(b * NH + h)) * S_LEN + qt * 64) * HD;
  #pragma unroll
  for (int i = 0; i < 4; i++) {
    int c = tid + 256 * i;
    int row = c >> 4, cc = c & 15;
    *(uint4*)&sQ[row * 136 + cc * 8] = *((const uint4*)(qsrc + (size_t)row * HD) + cc);
  }
  float mrow[4], lrow[4];
  #pragma unroll
  for (int r = 0; r < 4; r++) { mrow[r] = -__builtin_inff(); lrow[r] = 0.f; }
  f32x4 accO[8];
  #pragma unroll
  for (int i = 0; i < 8; i++) accO[i] = fzero4();

  const __bf16* kbase = kb + ((size_t)(b * NKV + kv)) * S_LEN * HD;
  const __bf16* vbase = vb + ((size_t)(b * NKV + kv)) * S_LEN * HD;

  for (int kt = 0; kt < 16; kt++) {
    __syncthreads();
    const __bf16* ksrc = kbase + (size_t)kt * 64 * HD;
    const __bf16* vsrc = vbase + (size_t)kt * 64 * HD;
    #pragma unroll
    for (int i = 0; i < 4; i++) {
      int c = tid + 256 * i;
      int row = c >> 4, cc = c & 15;
      *(uint4*)&sK[row * 136 + cc * 8] = *((const uint4*)(ksrc + (size_t)row * HD) + cc);
      uint4 v = *((const uint4*)(vsrc + (size_t)row * HD) + cc);
      unsigned vals[4] = {v.x, v.y, v.z, v.w};
      #pragma unroll
      for (int j = 0; j < 4; j++) {     // transpose into sVt[d][s]
        sVt[(cc * 8 + 2 * j) * 72 + row]     = us2bf((unsigned short)(vals[j] & 0xffffu));
        sVt[(cc * 8 + 2 * j + 1) * 72 + row] = us2bf((unsigned short)(vals[j] >> 16));
      }
    }
    __syncthreads();

    f32x4 accS[4];
    #pragma unroll
    for (int jt = 0; jt < 4; jt++) accS[jt] = fzero4();
    #pragma unroll
    for (int ks2 = 0; ks2 < 4; ks2++) {
      bf16x8 aF = *(const bf16x8*)&sQ[(wid * 16 + l16) * 136 + ks2 * 32 + quad * 8];
      #pragma unroll
      for (int jt = 0; jt < 4; jt++) {
        bf16x8 bF = *(const bf16x8*)&sK[(jt * 16 + l16) * 136 + ks2 * 32 + quad * 8];
        accS[jt] = __builtin_amdgcn_mfma_f32_16x16x32_bf16(aF, bF, accS[jt], 0, 0, 0);
      }
    }
    // online softmax; wave's row = 16*wid + quad*4 + r, cols in quad's 16 lanes
    float alpha[4];
    #pragma unroll
    for (int r = 0; r < 4; r++) {
      float mx = -__builtin_inff();
      #pragma unroll
      for (int jt = 0; jt < 4; jt++) {
        accS[jt][r] *= ATT_SCALE;
        mx = fmaxf(mx, accS[jt][r]);
      }
      #pragma unroll
      for (int m = 1; m <= 8; m <<= 1) mx = fmaxf(mx, __shfl_xor(mx, m, 64));
      float mn = fmaxf(mrow[r], mx);
      float al = __expf(mrow[r] - mn);
      float rs = 0.f;
      #pragma unroll
      for (int jt = 0; jt < 4; jt++) {
        float p = __expf(accS[jt][r] - mn);
        accS[jt][r] = p;
        rs += p;
      }
      #pragma unroll
      for (int m = 1; m <= 8; m <<= 1) rs += __shfl_xor(rs, m, 64);
      lrow[r] = lrow[r] * al + rs;
      mrow[r] = mn;
      alpha[r] = al;
    }
    #pragma unroll
    for (int nt = 0; nt < 8; nt++)
      #pragma unroll
      for (int r = 0; r < 4; r++) accO[nt][r] *= alpha[r];
    #pragma unroll
    for (int jt = 0; jt < 4; jt++)
      #pragma unroll
      for (int r = 0; r < 4; r++)
        sP[(wid * 16 + quad * 4 + r) * 72 + jt * 16 + l16] = f2bf(accS[jt][r]);
    __syncthreads();
    #pragma unroll
    for (int ks2 = 0; ks2 < 2; ks2++) {
      bf16x8 aF = *(const bf16x8*)&sP[(wid * 16 + l16) * 72 + ks2 * 32 + quad * 8];
      #pragma unroll
      for (int nt = 0; nt < 8; nt++) {
        bf16x8 bF = *(const bf16x8*)&sVt[(nt * 16 + l16) * 72 + ks2 * 32 + quad * 8];
        accO[nt] = __builtin_amdgcn_mfma_f32_16x16x32_bf16(aF, bF, accO[nt], 0, 0, 0);
      }
    }
  }
  #pragma unroll
  for (int nt = 0; nt < 8; nt++) {
    #pragma unroll
    for (int r = 0; r < 4; r++) {
      int srow = qt * 64 + wid * 16 + quad * 4 + r;
      float val = accO[nt][r] / lrow[r];
      outb[((size_t)(b * S_LEN + srow)) * H_DIM + h * HD + nt * 16 + l16] = f2bf(val);
    }
  }
}

// ---------------------------------------------------------------------------
// Router: recompute RMSNorm(hidden) fp32, logits vs 8 experts, sigmoid,
// grouped top-k (NG=4 groups of 2; group score = sum; top-2 groups; top-2
// experts among them; weights = sigmoid scores normalized). Builds gather
// lists; expert 8 = shared expert over all tokens.
// ---------------------------------------------------------------------------
__global__ __launch_bounds__(64) void router_k(
    const float* __restrict__ hid, const float* __restrict__ ln2w,
    const float* __restrict__ gw, const float* __restrict__ gb,
    int* __restrict__ cnt, int* __restrict__ list, float* __restrict__ wsl) {
  int t = blockIdx.x;
  int lane = threadIdx.x;
  const float* xr = hid + (size_t)t * H_DIM;
  float x[32];
  float ss = 0.f;
  #pragma unroll
  for (int j = 0; j < 32; j++) { x[j] = xr[j * 64 + lane]; ss += x[j] * x[j]; }
  #pragma unroll
  for (int m = 1; m <= 32; m <<= 1) ss += __shfl_xor(ss, m, 64);
  float sc = rsqrtf(ss * (1.f / H_DIM) + EPS);
  float xn[32];
  #pragma unroll
  for (int j = 0; j < 32; j++) xn[j] = x[j] * sc * ln2w[j * 64 + lane];
  float lg[8];
  #pragma unroll
  for (int e = 0; e < 8; e++) {
    float d = 0.f;
    #pragma unroll
    for (int j = 0; j < 32; j++) d += xn[j] * gw[(size_t)e * H_DIM + j * 64 + lane];
    #pragma unroll
    for (int m = 1; m <= 32; m <<= 1) d += __shfl_xor(d, m, 64);
    lg[e] = d;
  }
  float s[8], sb[8];
  #pragma unroll
  for (int e = 0; e < 8; e++) {
    s[e] = 1.f / (1.f + __expf(-lg[e]));
    sb[e] = s[e] + gb[e];
  }
  float gs[4];
  #pragma unroll
  for (int g = 0; g < 4; g++) gs[g] = sb[2 * g] + sb[2 * g + 1];
  int g1 = 0;
  for (int g = 1; g < 4; g++) if (gs[g] > gs[g1]) g1 = g;
  int g2 = -1;
  for (int g = 0; g < 4; g++) if (g != g1 && (g2 < 0 || gs[g] > gs[g2])) g2 = g;
  unsigned emask = (3u << (2 * g1)) | (3u << (2 * g2));
  int e1 = -1;
  for (int e = 0; e < 8; e++) if (((emask >> e) & 1u) && (e1 < 0 || sb[e] > sb[e1])) e1 = e;
  int e2 = -1;
  for (int e = 0; e < 8; e++) if (((emask >> e) & 1u) && e != e1 && (e2 < 0 || sb[e] > sb[e2])) e2 = e;
  float w1 = s[e1], w2 = s[e2];
  float dn = w1 + w2 + 1e-20f;
  w1 /= dn; w2 /= dn;   // RSF = 1.0
  if (lane == 0) {
    int p1 = atomicAdd(&cnt[e1], 1);
    list[e1 * T_TOK + p1] = t; wsl[e1 * T_TOK + p1] = w1;
    int p2 = atomicAdd(&cnt[e2], 1);
    list[e2 * T_TOK + p2] = t; wsl[e2 * T_TOK + p2] = w2;
    list[8 * T_TOK + t] = t; wsl[8 * T_TOK + t] = 1.f;   // shared expert
  }
}

// ---------------------------------------------------------------------------
// Gathered gate+up GEMM with fused silu-mul.
// he[e*T + slot, m] = silu(X[tok] . Wg[e,m]) * (X[tok] . Wu[e,m]), bf16 out.
// Tile 128(M) x 64(N), BK=64; wave w owns rows [32w, 32w+32).
// grid = (N/64=8, 16 token tiles, 9 experts); early-exit past cnt[e].
// ---------------------------------------------------------------------------
__global__ __launch_bounds__(256) void gemm_gateup(
    const __bf16* __restrict__ X, const float* __restrict__ weg,
    const float* __restrict__ weu, const float* __restrict__ wsg,
    const float* __restrict__ wsu, const int* __restrict__ list,
    const int* __restrict__ cnt, __bf16* __restrict__ he) {
  int e = blockIdx.z;
  int ne = (e == 8) ? T_TOK : cnt[e];
  int m0 = blockIdx.y * 128;
  if (m0 >= ne) return;
  int n0 = blockIdx.x * 64;
  const float* bg = (e < 8) ? weg + (size_t)e * MM * H_DIM : wsg;
  const float* bu = (e < 8) ? weu + (size_t)e * MM * H_DIM : wsu;
  const int* lst = list + e * T_TOK;
  __shared__ __bf16 sA[128 * 72];
  __shared__ __bf16 sBg[64 * 72];
  __shared__ __bf16 sBu[64 * 72];
  f32x4 ag[2][4], au[2][4];
  #pragma unroll
  for (int i = 0; i < 2; i++)
    #pragma unroll
    for (int j = 0; j < 4; j++) { ag[i][j] = fzero4(); au[i][j] = fzero4(); }

  int tid = threadIdx.x, lane = tid & 63, wid = tid >> 6;
  int quad = lane >> 4, l16 = lane & 15;

  for (int k0 = 0; k0 < H_DIM; k0 += 64) {
    __syncthreads();
    #pragma unroll
    for (int i = 0; i < 4; i++) {            // gathered A: 128 x 64 bf16
      int c = tid + 256 * i;
      int row = c >> 3, cc = c & 7;
      int r = m0 + row; if (r >= ne) r = ne - 1;
      int tk = lst[r];
      *(uint4*)&sA[row * 72 + cc * 8] =
          *((const uint4*)(X + (size_t)tk * H_DIM + k0) + cc);
    }
    #pragma unroll
    for (int i = 0; i < 4; i++) {            // Bg & Bu: 64 x 64 f32->bf16
      int c = tid + 256 * i;
      int row = c >> 4, cc = c & 15;
      float4 f = *((const float4*)(bg + (size_t)(n0 + row) * H_DIM + k0) + cc);
      bf16x4 hh;
      hh[0] = f2bf(f.x); hh[1] = f2bf(f.y); hh[2] = f2bf(f.z); hh[3] = f2bf(f.w);
      *(bf16x4*)&sBg[row * 72 + cc * 4] = hh;
      f = *((const float4*)(bu + (size_t)(n0 + row) * H_DIM + k0) + cc);
      hh[0] = f2bf(f.x); hh[1] = f2bf(f.y); hh[2] = f2bf(f.z); hh[3] = f2bf(f.w);
      *(bf16x4*)&sBu[row * 72 + cc * 4] = hh;
    }
    __syncthreads();
    #pragma unroll
    for (int ks = 0; ks < 64; ks += 32) {
      bf16x8 aF[2], gF[4], uF[4];
      #pragma unroll
      for (int mt = 0; mt < 2; mt++)
        aF[mt] = *(const bf16x8*)&sA[(wid*32 + mt*16 + l16) * 72 + ks + quad*8];
      #pragma unroll
      for (int nt = 0; nt < 4; nt++) {
        gF[nt] = *(const bf16x8*)&sBg[(nt*16 + l16) * 72 + ks + quad*8];
        uF[nt] = *(const bf16x8*)&sBu[(nt*16 + l16) * 72 + ks + quad*8];
      }
      #pragma unroll
      for (int mt = 0; mt < 2; mt++)
        #pragma unroll
        for (int nt = 0; nt < 4; nt++) {
          ag[mt][nt] = __builtin_amdgcn_mfma_f32_16x16x32_bf16(aF[mt], gF[nt], ag[mt][nt], 0, 0, 0);
          au[mt][nt] = __builtin_amdgcn_mfma_f32_16x16x32_bf16(aF[mt], uF[nt], au[mt][nt], 0, 0, 0);
        }
    }
  }
  #pragma unroll
  for (int mt = 0; mt < 2; mt++) {
    #pragma unroll
    for (int nt = 0; nt < 4; nt++) {
      #pragma unroll
      for (int r = 0; r < 4; r++) {
        int row_l = wid * 32 + mt * 16 + quad * 4 + r;
        int grow = m0 + row_l;
        if (grow < ne) {
          float g = ag[mt][nt][r], u = au[mt][nt][r];
          float hv = g / (1.f + __expf(-g)) * u;     // silu(g)*u
          he[((size_t)e * T_TOK + grow) * MM + n0 + nt * 16 + l16] = f2bf(hv);
        }
      }
    }
  }
}

// ---------------------------------------------------------------------------
extern "C" void kernel_launch(void* const* d_in, const int* in_sizes, int n_in,
                              void* d_out, int out_size, void* d_ws, size_t ws_size,
                              hipStream_t stream) {
  (void)in_sizes; (void)n_in; (void)out_size; (void)ws_size;
  const float* hs     = (const float*)d_in[0];
  const float* cosp   = (const float*)d_in[1];
  const float* sinp   = (const float*)d_in[2];
  const float* ln1w   = (const float*)d_in[3];
  const float* wqkv   = (const float*)d_in[4];
  const float* qlw    = (const float*)d_in[5];
  const float* klw    = (const float*)d_in[6];
  const float* wdense = (const float*)d_in[7];
  const float* ln2w   = (const float*)d_in[8];
  const float* gw     = (const float*)d_in[9];
  const float* gbias  = (const float*)d_in[10];
  const float* weg    = (const float*)d_in[11];
  const float* weu    = (const float*)d_in[12];
  const float* wed    = (const float*)d_in[13];
  const float* wsg    = (const float*)d_in[14];
  const float* wsu    = (const float*)d_in[15];
  const float* wsd    = (const float*)d_in[16];
  float* out = (float*)d_out;

  char* ws = (char*)d_ws;
  size_t off = 0;
  auto alloc = [&](size_t b) { char* p = ws + off; off += (b + 255) & ~(size_t)255; return p; };
  __bf16* xb1   = (__bf16*)alloc((size_t)T_TOK * H_DIM * 2);          // 8 MB
  float*  qkv32 = (float*) alloc((size_t)T_TOK * QKV_O * 4);          // 25 MB
  __bf16* qb    = (__bf16*)alloc((size_t)2 * NH  * S_LEN * HD * 2);   // 8 MB
  __bf16* kb    = (__bf16*)alloc((size_t)2 * NKV * S_LEN * HD * 2);   // 2 MB
  __bf16* vb    = (__bf16*)alloc((size_t)2 * NKV * S_LEN * HD * 2);   // 2 MB
  __bf16* outb  = (__bf16*)alloc((size_t)T_TOK * H_DIM * 2);          // 8 MB
  __bf16* xb2   = (__bf16*)alloc((size_t)T_TOK * H_DIM * 2);          // 8 MB
  int*    cnt   = (int*)   alloc(256);
  int*    list  = (int*)   alloc((size_t)9 * T_TOK * 4);
  float*  wsl   = (float*) alloc((size_t)9 * T_TOK * 4);
  __bf16* he    = (__bf16*)qkv32;  // overlap: he (18.9 MB) reuses dead qkv32 (25.2 MB)

  hipMemsetAsync(cnt, 0, 256, stream);
  // 1) x = rmsnorm(hidden, ln1_w) -> bf16
  rmsnorm_k<<<T_TOK, 256, 0, stream>>>(hs, ln1w, xb1);
  // 2) qkv = x @ w_qkv^T (fp32 out)
  gemm_nt<0><<<dim3(QKV_O / 128, T_TOK / 128), 256, 0, stream>>>(
      xb1, wqkv, nullptr, qkv32, nullptr, nullptr, nullptr, nullptr, QKV_O, H_DIM);
  // 3) q/k norm + rope, v cast -> bf16 (b,h,s,d)
  rope_k<<<T_TOK * 24, 64, 0, stream>>>(qkv32, qlw, klw, cosp, sinp, qb, kb, vb);
  // 4) flash attention -> outb bf16 (t, nh*hd)
  flash_k<<<dim3(S_LEN / 64, 2 * NH), 256, 0, stream>>>(qb, kb, vb, outb);
  // 5) hidden = hs + outb @ w_dense^T  -> d_out (fp32)
  gemm_nt<1><<<dim3(H_DIM / 128, T_TOK / 128), 256, 0, stream>>>(
      outb, wdense, nullptr, out, hs, nullptr, nullptr, nullptr, H_DIM, H_DIM);
  // 6) x2 = rmsnorm(hidden, ln2_w) -> bf16
  rmsnorm_k<<<T_TOK, 256, 0, stream>>>(out, ln2w, xb2);
  // 7) router: top-2-of-8 grouped, build gather lists (expert 8 = shared)
  router_k<<<T_TOK, 64, 0, stream>>>(out, ln2w, gw, gbias, cnt, list, wsl);
  // 8) gathered gate/up + silu-mul -> he bf16
  gemm_gateup<<<dim3(MM / 64, T_TOK / 128, 9), 256, 0, stream>>>(
      xb2, weg, weu, wsg, wsu, list, cnt, he);
  // 9) down-proj + weighted scatter-add into d_out
  gemm_nt<2><<<dim3(H_DIM / 128, T_TOK / 128, 9), 256, 0, stream>>>(
      he, wed, wsd, out, nullptr, list, wsl, cnt, H_DIM, MM);
}

// Round 2
// 548.189 us; speedup vs baseline: 1.1440x; 1.1440x over previous
//
#include <hip/hip_runtime.h>
#include <cstdint>
#include <cstddef>

#define T_TOK 2048
#define H_DIM 2048
#define S_LEN 1024
#define HD 128
#define NH 16
#define NKV 4
#define QKV_O 3072
#define MM 512
#define EPS 1e-6f
#define ATT_SCALE 0.08838834764831845f  // 128^-0.5

typedef __bf16 bf16x8 __attribute__((ext_vector_type(8)));
typedef __bf16 bf16x4 __attribute__((ext_vector_type(4)));
typedef float  f32x4  __attribute__((ext_vector_type(4)));

__device__ __forceinline__ __bf16 f2bf(float f) {
  unsigned u = __builtin_bit_cast(unsigned, f);
  u += 0x7fffu + ((u >> 16) & 1u);           // RNE; inputs are finite
  unsigned short h = (unsigned short)(u >> 16);
  return __builtin_bit_cast(__bf16, h);
}
__device__ __forceinline__ f32x4 fzero4() {
  f32x4 z; z[0] = 0.f; z[1] = 0.f; z[2] = 0.f; z[3] = 0.f; return z;
}
// async global->LDS, 16B per lane. LDS dest = wave-uniform base + lane*16;
// we pass base+lane*16 per-lane which is consistent either way.
__device__ __forceinline__ void gld16(const __bf16* g, __bf16* l) {
  __builtin_amdgcn_global_load_lds(
      (const __attribute__((address_space(1))) unsigned int*)g,
      (__attribute__((address_space(3))) unsigned int*)l, 16, 0, 0);
}

// ---------------------------------------------------------------------------
// Weight fp32 -> bf16 conversion (one pass over all 8 weight tensors).
// ---------------------------------------------------------------------------
__global__ __launch_bounds__(256) void wconv_k(
    const float* __restrict__ s0, const float* __restrict__ s1,
    const float* __restrict__ s2, const float* __restrict__ s3,
    const float* __restrict__ s4, const float* __restrict__ s5,
    const float* __restrict__ s6, const float* __restrict__ s7,
    __bf16* __restrict__ dst) {
  size_t e = ((size_t)blockIdx.x * 256 + threadIdx.x) * 4;
  const size_t E0 = 6291456, E1 = 10485760, E2 = 18874368, E3 = 27262976,
               E4 = 35651584, E5 = 36700160, E6 = 37748736;
  const float* src; size_t base;
  if      (e < E0) { src = s0; base = 0;  }
  else if (e < E1) { src = s1; base = E0; }
  else if (e < E2) { src = s2; base = E1; }
  else if (e < E3) { src = s3; base = E2; }
  else if (e < E4) { src = s4; base = E3; }
  else if (e < E5) { src = s5; base = E4; }
  else if (e < E6) { src = s6; base = E5; }
  else             { src = s7; base = E6; }
  float4 f = *(const float4*)(src + (e - base));
  bf16x4 o;
  o[0] = f2bf(f.x); o[1] = f2bf(f.y); o[2] = f2bf(f.z); o[3] = f2bf(f.w);
  *(bf16x4*)(dst + e) = o;
}

// ---------------------------------------------------------------------------
// RMSNorm over H=2048, fp32 in -> bf16 out. One block (256 thr) per token.
// ---------------------------------------------------------------------------
__global__ __launch_bounds__(256) void rmsnorm_k(const float* __restrict__ X,
                                                 const float* __restrict__ W,
                                                 __bf16* __restrict__ Y) {
  int t = blockIdx.x;
  int tid = threadIdx.x, lane = tid & 63, wid = tid >> 6;
  const float4* row = (const float4*)(X + (size_t)t * H_DIM);
  float4 v0 = row[tid], v1 = row[tid + 256];
  float ss = v0.x*v0.x + v0.y*v0.y + v0.z*v0.z + v0.w*v0.w
           + v1.x*v1.x + v1.y*v1.y + v1.z*v1.z + v1.w*v1.w;
  #pragma unroll
  for (int m = 1; m <= 32; m <<= 1) ss += __shfl_xor(ss, m, 64);
  __shared__ float red[4];
  if (lane == 0) red[wid] = ss;
  __syncthreads();
  float tot = red[0] + red[1] + red[2] + red[3];
  float sc = rsqrtf(tot * (1.f / H_DIM) + EPS);
  const float4* wp = (const float4*)W;
  float4 w0 = wp[tid], w1 = wp[tid + 256];
  bf16x4 o;
  o[0] = f2bf(v0.x*w0.x*sc); o[1] = f2bf(v0.y*w0.y*sc);
  o[2] = f2bf(v0.z*w0.z*sc); o[3] = f2bf(v0.w*w0.w*sc);
  *(bf16x4*)&Y[(size_t)t*H_DIM + tid*4] = o;
  o[0] = f2bf(v1.x*w1.x*sc); o[1] = f2bf(v1.y*w1.y*sc);
  o[2] = f2bf(v1.z*w1.z*sc); o[3] = f2bf(v1.w*w1.w*sc);
  *(bf16x4*)&Y[(size_t)t*H_DIM + 1024 + tid*4] = o;
}

// ---------------------------------------------------------------------------
// NT GEMM, m97-style: both operands bf16, staged via global_load_lds(16B)
// with XOR chunk swizzle (slot(row,sc) holds global chunk sc^(row&7)).
// Tile 128x128, BK=64, 4 waves of 64x64, mfma 16x16x32 bf16.
// MODE 0: C fp32 plain store (ldc=N)
// MODE 1: C fp32 = acc + resid (ldc=2048)
// MODE 2: expert down-proj: grid.z=expert, scatter atomicAdd w/ weight
// ---------------------------------------------------------------------------
template<int MODE>
__global__ __launch_bounds__(256) void gemm_nt(
    const __bf16* __restrict__ A, const __bf16* __restrict__ B,
    const __bf16* __restrict__ B2, float* __restrict__ C,
    const float* __restrict__ resid, const int* __restrict__ list,
    const float* __restrict__ wsl, const int* __restrict__ cnt,
    int N, int K) {
  int e  = (MODE == 2) ? (int)blockIdx.z : 0;
  int ne = (MODE == 2) ? ((e == 8) ? T_TOK : cnt[e]) : T_TOK;
  int m0 = blockIdx.y * 128;
  if (MODE == 2 && m0 >= ne) return;
  int n0 = blockIdx.x * 128;
  const __bf16* Ab = A;
  const __bf16* Bb = B;
  if (MODE == 2) {
    Ab = A + (size_t)e * T_TOK * MM;
    Bb = (e < 8) ? B + (size_t)e * H_DIM * MM : B2;
  }
  __shared__ __bf16 sA[128 * 64];
  __shared__ __bf16 sB[128 * 64];
  int tid = threadIdx.x, lane = tid & 63, wid = tid >> 6;
  int quad = lane >> 4, l16 = lane & 15;
  int wm = wid & 1, wn = wid >> 1;

  const __bf16* gA[4]; const __bf16* gB[4];
  #pragma unroll
  for (int i = 0; i < 4; i++) {
    int p = tid + 256 * i;
    int row = p >> 3, sc = p & 7, gc = sc ^ (row & 7);
    gA[i] = Ab + (size_t)(m0 + row) * K + gc * 8;
    gB[i] = Bb + (size_t)(n0 + row) * K + gc * 8;
  }
  f32x4 acc[4][4];
  #pragma unroll
  for (int i = 0; i < 4; i++)
    #pragma unroll
    for (int j = 0; j < 4; j++) acc[i][j] = fzero4();

  for (int k0 = 0; k0 < K; k0 += 64) {
    __syncthreads();
    #pragma unroll
    for (int i = 0; i < 4; i++) {
      gld16(gA[i] + k0, &sA[(tid + 256 * i) * 8]);
      gld16(gB[i] + k0, &sB[(tid + 256 * i) * 8]);
    }
    __syncthreads();
    #pragma unroll
    for (int ks = 0; ks < 64; ks += 32) {
      int cb = ks >> 3;  // chunk base: 0 or 4
      bf16x8 aF[4], bF[4];
      #pragma unroll
      for (int mt = 0; mt < 4; mt++) {
        int row = wm * 64 + mt * 16 + l16;
        int pos = row * 8 + ((cb + quad) ^ (row & 7));
        aF[mt] = *(const bf16x8*)&sA[pos * 8];
      }
      #pragma unroll
      for (int nt = 0; nt < 4; nt++) {
        int row = wn * 64 + nt * 16 + l16;
        int pos = row * 8 + ((cb + quad) ^ (row & 7));
        bF[nt] = *(const bf16x8*)&sB[pos * 8];
      }
      #pragma unroll
      for (int mt = 0; mt < 4; mt++)
        #pragma unroll
        for (int nt = 0; nt < 4; nt++)
          acc[mt][nt] = __builtin_amdgcn_mfma_f32_16x16x32_bf16(
              aF[mt], bF[nt], acc[mt][nt], 0, 0, 0);
    }
  }
  // Epilogue. C-layout: row = quad*4+reg, col = lane&15 (m89-verified).
  #pragma unroll
  for (int mt = 0; mt < 4; mt++) {
    #pragma unroll
    for (int nt = 0; nt < 4; nt++) {
      #pragma unroll
      for (int r = 0; r < 4; r++) {
        int row_l = wm*64 + mt*16 + quad*4 + r;
        int col_l = wn*64 + nt*16 + l16;
        int grow = m0 + row_l, gcol = n0 + col_l;
        float val = acc[mt][nt][r];
        if (MODE == 0) {
          C[(size_t)grow * N + gcol] = val;
        } else if (MODE == 1) {
          C[(size_t)grow * H_DIM + gcol] = val + resid[(size_t)grow * H_DIM + gcol];
        } else {
          if (grow < ne) {
            int tk  = list[e * T_TOK + grow];
            float w = wsl[e * T_TOK + grow];
            atomicAdd(&C[(size_t)tk * H_DIM + gcol], val * w);
          }
        }
      }
    }
  }
}

// ---------------------------------------------------------------------------
// Per (token, head): q/k RMSNorm (HD=128) + RoPE, v passthrough; fp32->bf16.
// 256-thread blocks = 4 heads; wave handles one head, lane d holds d, d+64.
// ---------------------------------------------------------------------------
__global__ __launch_bounds__(256) void rope_k(
    const float* __restrict__ qkv, const float* __restrict__ qlw,
    const float* __restrict__ klw, const float* __restrict__ cosp,
    const float* __restrict__ sinp, __bf16* __restrict__ qb,
    __bf16* __restrict__ kb, __bf16* __restrict__ vb) {
  int bid = blockIdx.x;                 // T_TOK * 6
  int t = bid / 6;
  int head = (bid % 6) * 4 + (threadIdx.x >> 6);
  int b = t >> 10, s = t & 1023;
  int d = threadIdx.x & 63;
  const float* src = qkv + (size_t)t * QKV_O + head * HD;
  float x1 = src[d], x2 = src[d + 64];
  if (head < 20) {
    float ssq = x1*x1 + x2*x2;
    #pragma unroll
    for (int m = 1; m <= 32; m <<= 1) ssq += __shfl_xor(ssq, m, 64);
    float sc = rsqrtf(ssq * (1.f / HD) + EPS);
    const float* w = (head < 16) ? qlw : klw;
    x1 = x1 * sc * w[d];
    x2 = x2 * sc * w[d + 64];
    size_t cb = (size_t)t * HD;
    float c1 = cosp[cb + d], s1 = sinp[cb + d];
    float c2 = cosp[cb + d + 64], s2 = sinp[cb + d + 64];
    float o1 = x1 * c1 - x2 * s1;
    float o2 = x2 * c2 + x1 * s2;
    if (head < 16) {
      __bf16* dst = qb + (((size_t)(b * NH + head)) * S_LEN + s) * HD;
      dst[d] = f2bf(o1); dst[d + 64] = f2bf(o2);
    } else {
      int kv = head - 16;
      __bf16* dst = kb + (((size_t)(b * NKV + kv)) * S_LEN + s) * HD;
      dst[d] = f2bf(o1); dst[d + 64] = f2bf(o2);
    }
  } else {
    int kv = head - 20;
    __bf16* dst = vb + (((size_t)(b * NKV + kv)) * S_LEN + s) * HD;
    dst[d] = f2bf(x1); dst[d + 64] = f2bf(x2);
  }
}

// ---------------------------------------------------------------------------
// V transpose: vb [g][s][d] -> vt [g][d][s]  (g = b*NKV+kv), 64x64 tiles.
// ---------------------------------------------------------------------------
__global__ __launch_bounds__(256) void vtrans_k(const __bf16* __restrict__ vb,
                                                __bf16* __restrict__ vt) {
  int s0 = blockIdx.x * 64, d0 = blockIdx.y * 64, g = blockIdx.z;
  __shared__ __bf16 sT[64 * 80];
  int tid = threadIdx.x;
  const __bf16* src = vb + (size_t)g * S_LEN * HD;
  #pragma unroll
  for (int i = 0; i < 2; i++) {
    int p = tid + 256 * i;
    int rs = p >> 3, cc = p & 7;
    bf16x8 v = *(const bf16x8*)(src + (size_t)(s0 + rs) * HD + d0 + cc * 8);
    #pragma unroll
    for (int j = 0; j < 8; j++) sT[(cc * 8 + j) * 80 + rs] = v[j];
  }
  __syncthreads();
  __bf16* dst = vt + (size_t)g * HD * S_LEN;
  #pragma unroll
  for (int i = 0; i < 2; i++) {
    int p = tid + 256 * i;
    int rd = p >> 3, cs = p & 7;
    bf16x8 v = *(const bf16x8*)&sT[rd * 80 + cs * 8];
    *(bf16x8*)(dst + (size_t)(d0 + rd) * S_LEN + s0 + cs * 8) = v;
  }
}

// ---------------------------------------------------------------------------
// Flash attention v2. 64-row Q tile, 64-col K/V tiles, global_load_lds
// staging with XOR swizzle, Vt pre-transposed globally, sP unioned onto sK.
// LDS = 48KB -> 3 blocks/CU.
// ---------------------------------------------------------------------------
__global__ __launch_bounds__(256) void flash_k(
    const __bf16* __restrict__ qb, const __bf16* __restrict__ kb,
    const __bf16* __restrict__ vt, __bf16* __restrict__ outb) {
  int qt = blockIdx.x, bh = blockIdx.y;
  int b = bh >> 4, h = bh & 15, kv = h >> 2;
  int tid = threadIdx.x, lane = tid & 63, wid = tid >> 6;
  int quad = lane >> 4, l16 = lane & 15;
  __shared__ __bf16 sQ[64 * 128];
  __shared__ __bf16 sKP[64 * 128];      // sK; reused as sP (64*72) after (c)
  __shared__ __bf16 sVt[128 * 64];
  __bf16* sK = sKP;
  __bf16* sP = sKP;

  // stage Q once (swizzled, 16-chunk rows)
  const __bf16* qsrc = qb + (((size_t)(b * NH + h)) * S_LEN + qt * 64) * HD;
  #pragma unroll
  for (int i = 0; i < 4; i++) {
    int p = tid + 256 * i;
    int row = p >> 4, sc = p & 15, gc = sc ^ (row & 7);
    gld16(qsrc + (size_t)row * HD + gc * 8, &sQ[p * 8]);
  }
  const __bf16* kbase  = kb + ((size_t)(b * NKV + kv)) * S_LEN * HD;
  const __bf16* vtbase = vt + ((size_t)(b * NKV + kv)) * HD * S_LEN;
  const __bf16* gK[4]; const __bf16* gV[4];
  #pragma unroll
  for (int i = 0; i < 4; i++) {
    int p = tid + 256 * i;
    int rowk = p >> 4, sck = p & 15, gck = sck ^ (rowk & 7);
    gK[i] = kbase + (size_t)rowk * HD + gck * 8;
    int rowv = p >> 3, scv = p & 7, gcv = scv ^ (rowv & 7);
    gV[i] = vtbase + (size_t)rowv * S_LEN + gcv * 8;
  }
  float mrow[4], lrow[4];
  #pragma unroll
  for (int r = 0; r < 4; r++) { mrow[r] = -__builtin_inff(); lrow[r] = 0.f; }
  f32x4 accO[8];
  #pragma unroll
  for (int i = 0; i < 8; i++) accO[i] = fzero4();

  for (int kt = 0; kt < 16; kt++) {
    __syncthreads();                         // (a) prev PV done (also Q drain)
    #pragma unroll
    for (int i = 0; i < 4; i++) {
      gld16(gK[i] + (size_t)kt * 64 * HD, &sK[(tid + 256 * i) * 8]);
      gld16(gV[i] + kt * 64, &sVt[(tid + 256 * i) * 8]);
    }
    __syncthreads();                         // (b) staging visible
    // S = Q K^T
    f32x4 accS[4];
    #pragma unroll
    for (int jt = 0; jt < 4; jt++) accS[jt] = fzero4();
    int rowA = wid * 16 + l16;
    #pragma unroll
    for (int ks2 = 0; ks2 < 4; ks2++) {
      int posA = rowA * 16 + ((ks2 * 4 + quad) ^ (rowA & 7));
      bf16x8 aF = *(const bf16x8*)&sQ[posA * 8];
      #pragma unroll
      for (int jt = 0; jt < 4; jt++) {
        int rowB = jt * 16 + l16;
        int posB = rowB * 16 + ((ks2 * 4 + quad) ^ (rowB & 7));
        bf16x8 bF = *(const bf16x8*)&sK[posB * 8];
        accS[jt] = __builtin_amdgcn_mfma_f32_16x16x32_bf16(aF, bF, accS[jt], 0, 0, 0);
      }
    }
    // online softmax
    float alpha[4];
    #pragma unroll
    for (int r = 0; r < 4; r++) {
      float mx = -__builtin_inff();
      #pragma unroll
      for (int jt = 0; jt < 4; jt++) {
        accS[jt][r] *= ATT_SCALE;
        mx = fmaxf(mx, accS[jt][r]);
      }
      #pragma unroll
      for (int m = 1; m <= 8; m <<= 1) mx = fmaxf(mx, __shfl_xor(mx, m, 64));
      float mn = fmaxf(mrow[r], mx);
      float al = __expf(mrow[r] - mn);
      float rs = 0.f;
      #pragma unroll
      for (int jt = 0; jt < 4; jt++) {
        float p = __expf(accS[jt][r] - mn);
        accS[jt][r] = p;
        rs += p;
      }
      #pragma unroll
      for (int m = 1; m <= 8; m <<= 1) rs += __shfl_xor(rs, m, 64);
      lrow[r] = lrow[r] * al + rs;
      mrow[r] = mn;
      alpha[r] = al;
    }
    #pragma unroll
    for (int nt = 0; nt < 8; nt++)
      #pragma unroll
      for (int r = 0; r < 4; r++) accO[nt][r] *= alpha[r];
    __syncthreads();                         // (c) all waves done reading sK
    #pragma unroll
    for (int jt = 0; jt < 4; jt++)
      #pragma unroll
      for (int r = 0; r < 4; r++)
        sP[(wid * 16 + quad * 4 + r) * 72 + jt * 16 + l16] = f2bf(accS[jt][r]);
    __syncthreads();                         // (d) sP visible
    // O += P V   (Vt rows = d, swizzled 8-chunk rows)
    #pragma unroll
    for (int ks2 = 0; ks2 < 2; ks2++) {
      bf16x8 aF = *(const bf16x8*)&sP[(wid * 16 + l16) * 72 + ks2 * 32 + quad * 8];
      #pragma unroll
      for (int nt = 0; nt < 8; nt++) {
        int rowB = nt * 16 + l16;
        int posB = rowB * 8 + ((ks2 * 4 + quad) ^ (rowB & 7));
        bf16x8 bF = *(const bf16x8*)&sVt[posB * 8];
        accO[nt] = __builtin_amdgcn_mfma_f32_16x16x32_bf16(aF, bF, accO[nt], 0, 0, 0);
      }
    }
  }
  #pragma unroll
  for (int nt = 0; nt < 8; nt++) {
    #pragma unroll
    for (int r = 0; r < 4; r++) {
      int srow = qt * 64 + wid * 16 + quad * 4 + r;
      float val = accO[nt][r] / lrow[r];
      outb[((size_t)(b * S_LEN + srow)) * H_DIM + h * HD + nt * 16 + l16] = f2bf(val);
    }
  }
}

// ---------------------------------------------------------------------------
// Router (unchanged).
// ---------------------------------------------------------------------------
__global__ __launch_bounds__(64) void router_k(
    const float* __restrict__ hid, const float* __restrict__ ln2w,
    const float* __restrict__ gw, const float* __restrict__ gb,
    int* __restrict__ cnt, int* __restrict__ list, float* __restrict__ wsl) {
  int t = blockIdx.x;
  int lane = threadIdx.x;
  const float* xr = hid + (size_t)t * H_DIM;
  float x[32];
  float ss = 0.f;
  #pragma unroll
  for (int j = 0; j < 32; j++) { x[j] = xr[j * 64 + lane]; ss += x[j] * x[j]; }
  #pragma unroll
  for (int m = 1; m <= 32; m <<= 1) ss += __shfl_xor(ss, m, 64);
  float sc = rsqrtf(ss * (1.f / H_DIM) + EPS);
  float xn[32];
  #pragma unroll
  for (int j = 0; j < 32; j++) xn[j] = x[j] * sc * ln2w[j * 64 + lane];
  float lg[8];
  #pragma unroll
  for (int e = 0; e < 8; e++) {
    float d = 0.f;
    #pragma unroll
    for (int j = 0; j < 32; j++) d += xn[j] * gw[(size_t)e * H_DIM + j * 64 + lane];
    #pragma unroll
    for (int m = 1; m <= 32; m <<= 1) d += __shfl_xor(d, m, 64);
    lg[e] = d;
  }
  float s[8], sb[8];
  #pragma unroll
  for (int e = 0; e < 8; e++) {
    s[e] = 1.f / (1.f + __expf(-lg[e]));
    sb[e] = s[e] + gb[e];
  }
  float gs[4];
  #pragma unroll
  for (int g = 0; g < 4; g++) gs[g] = sb[2 * g] + sb[2 * g + 1];
  int g1 = 0;
  for (int g = 1; g < 4; g++) if (gs[g] > gs[g1]) g1 = g;
  int g2 = -1;
  for (int g = 0; g < 4; g++) if (g != g1 && (g2 < 0 || gs[g] > gs[g2])) g2 = g;
  unsigned emask = (3u << (2 * g1)) | (3u << (2 * g2));
  int e1 = -1;
  for (int e = 0; e < 8; e++) if (((emask >> e) & 1u) && (e1 < 0 || sb[e] > sb[e1])) e1 = e;
  int e2 = -1;
  for (int e = 0; e < 8; e++) if (((emask >> e) & 1u) && e != e1 && (e2 < 0 || sb[e] > sb[e2])) e2 = e;
  float w1 = s[e1], w2 = s[e2];
  float dn = w1 + w2 + 1e-20f;
  w1 /= dn; w2 /= dn;   // RSF = 1.0
  if (lane == 0) {
    int p1 = atomicAdd(&cnt[e1], 1);
    list[e1 * T_TOK + p1] = t; wsl[e1 * T_TOK + p1] = w1;
    int p2 = atomicAdd(&cnt[e2], 1);
    list[e2 * T_TOK + p2] = t; wsl[e2 * T_TOK + p2] = w2;
    list[8 * T_TOK + t] = t; wsl[8 * T_TOK + t] = 1.f;   // shared expert
  }
}

// ---------------------------------------------------------------------------
// Gathered gate+up GEMM with fused silu-mul (m97-style staging).
// Tile 128(M) x 64(N), BK=64; wave w owns rows [32w, 32w+32).
// ---------------------------------------------------------------------------
__global__ __launch_bounds__(256) void gemm_gateup(
    const __bf16* __restrict__ X, const __bf16* __restrict__ weg,
    const __bf16* __restrict__ weu, const __bf16* __restrict__ wsg,
    const __bf16* __restrict__ wsu, const int* __restrict__ list,
    const int* __restrict__ cnt, __bf16* __restrict__ he) {
  int e = blockIdx.z;
  int ne = (e == 8) ? T_TOK : cnt[e];
  int m0 = blockIdx.y * 128;
  if (m0 >= ne) return;
  int n0 = blockIdx.x * 64;
  const __bf16* bg = (e < 8) ? weg + (size_t)e * MM * H_DIM : wsg;
  const __bf16* bu = (e < 8) ? weu + (size_t)e * MM * H_DIM : wsu;
  const int* lst = list + e * T_TOK;
  __shared__ __bf16 sA[128 * 64];
  __shared__ __bf16 sBg[64 * 64];
  __shared__ __bf16 sBu[64 * 64];
  int tid = threadIdx.x, lane = tid & 63, wid = tid >> 6;
  int quad = lane >> 4, l16 = lane & 15;

  const __bf16* gA[4]; const __bf16* gBg[2]; const __bf16* gBu[2];
  #pragma unroll
  for (int i = 0; i < 4; i++) {
    int p = tid + 256 * i;
    int row = p >> 3, sc = p & 7, gc = sc ^ (row & 7);
    int r = m0 + row; if (r >= ne) r = ne - 1;
    int tk = lst[r];
    gA[i] = X + (size_t)tk * H_DIM + gc * 8;
  }
  #pragma unroll
  for (int i = 0; i < 2; i++) {
    int p = tid + 256 * i;
    int row = p >> 3, sc = p & 7, gc = sc ^ (row & 7);
    gBg[i] = bg + (size_t)(n0 + row) * H_DIM + gc * 8;
    gBu[i] = bu + (size_t)(n0 + row) * H_DIM + gc * 8;
  }
  f32x4 ag[2][4], au[2][4];
  #pragma unroll
  for (int i = 0; i < 2; i++)
    #pragma unroll
    for (int j = 0; j < 4; j++) { ag[i][j] = fzero4(); au[i][j] = fzero4(); }

  for (int k0 = 0; k0 < H_DIM; k0 += 64) {
    __syncthreads();
    #pragma unroll
    for (int i = 0; i < 4; i++)
      gld16(gA[i] + k0, &sA[(tid + 256 * i) * 8]);
    #pragma unroll
    for (int i = 0; i < 2; i++) {
      gld16(gBg[i] + k0, &sBg[(tid + 256 * i) * 8]);
      gld16(gBu[i] + k0, &sBu[(tid + 256 * i) * 8]);
    }
    __syncthreads();
    #pragma unroll
    for (int ks = 0; ks < 64; ks += 32) {
      int cb = ks >> 3;
      bf16x8 aF[2], gF[4], uF[4];
      #pragma unroll
      for (int mt = 0; mt < 2; mt++) {
        int row = wid * 32 + mt * 16 + l16;
        int pos = row * 8 + ((cb + quad) ^ (row & 7));
        aF[mt] = *(const bf16x8*)&sA[pos * 8];
      }
      #pragma unroll
      for (int nt = 0; nt < 4; nt++) {
        int row = nt * 16 + l16;
        int pos = row * 8 + ((cb + quad) ^ (row & 7));
        gF[nt] = *(const bf16x8*)&sBg[pos * 8];
        uF[nt] = *(const bf16x8*)&sBu[pos * 8];
      }
      #pragma unroll
      for (int mt = 0; mt < 2; mt++)
        #pragma unroll
        for (int nt = 0; nt < 4; nt++) {
          ag[mt][nt] = __builtin_amdgcn_mfma_f32_16x16x32_bf16(aF[mt], gF[nt], ag[mt][nt], 0, 0, 0);
          au[mt][nt] = __builtin_amdgcn_mfma_f32_16x16x32_bf16(aF[mt], uF[nt], au[mt][nt], 0, 0, 0);
        }
    }
  }
  #pragma unroll
  for (int mt = 0; mt < 2; mt++) {
    #pragma unroll
    for (int nt = 0; nt < 4; nt++) {
      #pragma unroll
      for (int r = 0; r < 4; r++) {
        int row_l = wid * 32 + mt * 16 + quad * 4 + r;
        int grow = m0 + row_l;
        if (grow < ne) {
          float g = ag[mt][nt][r], u = au[mt][nt][r];
          float hv = g / (1.f + __expf(-g)) * u;     // silu(g)*u
          he[((size_t)e * T_TOK + grow) * MM + n0 + nt * 16 + l16] = f2bf(hv);
        }
      }
    }
  }
}

// ---------------------------------------------------------------------------
extern "C" void kernel_launch(void* const* d_in, const int* in_sizes, int n_in,
                              void* d_out, int out_size, void* d_ws, size_t ws_size,
                              hipStream_t stream) {
  (void)in_sizes; (void)n_in; (void)out_size; (void)ws_size;
  const float* hs     = (const float*)d_in[0];
  const float* cosp   = (const float*)d_in[1];
  const float* sinp   = (const float*)d_in[2];
  const float* ln1w   = (const float*)d_in[3];
  const float* wqkv   = (const float*)d_in[4];
  const float* qlw    = (const float*)d_in[5];
  const float* klw    = (const float*)d_in[6];
  const float* wdense = (const float*)d_in[7];
  const float* ln2w   = (const float*)d_in[8];
  const float* gw     = (const float*)d_in[9];
  const float* gbias  = (const float*)d_in[10];
  const float* weg    = (const float*)d_in[11];
  const float* weu    = (const float*)d_in[12];
  const float* wed    = (const float*)d_in[13];
  const float* wsg    = (const float*)d_in[14];
  const float* wsu    = (const float*)d_in[15];
  const float* wsd    = (const float*)d_in[16];
  float* out = (float*)d_out;

  char* ws = (char*)d_ws;
  size_t off = 0;
  auto alloc = [&](size_t b) { char* p = ws + off; off += (b + 255) & ~(size_t)255; return p; };
  __bf16* wbf   = (__bf16*)alloc((size_t)38797312 * 2);               // 74 MB
  __bf16* xb1   = (__bf16*)alloc((size_t)T_TOK * H_DIM * 2);
  float*  qkv32 = (float*) alloc((size_t)T_TOK * QKV_O * 4);
  __bf16* qb    = (__bf16*)alloc((size_t)2 * NH  * S_LEN * HD * 2);
  __bf16* kb    = (__bf16*)alloc((size_t)2 * NKV * S_LEN * HD * 2);
  __bf16* vb    = (__bf16*)alloc((size_t)2 * NKV * S_LEN * HD * 2);
  __bf16* vt    = (__bf16*)alloc((size_t)2 * NKV * S_LEN * HD * 2);
  __bf16* outb  = (__bf16*)alloc((size_t)T_TOK * H_DIM * 2);
  __bf16* xb2   = (__bf16*)alloc((size_t)T_TOK * H_DIM * 2);
  int*    cnt   = (int*)   alloc(256);
  int*    list  = (int*)   alloc((size_t)9 * T_TOK * 4);
  float*  wsl   = (float*) alloc((size_t)9 * T_TOK * 4);
  __bf16* he    = (__bf16*)qkv32;   // he (18.9 MB) reuses dead qkv32 (25.2 MB)

  const __bf16* wqkv_bf   = wbf;
  const __bf16* wdense_bf = wbf + 6291456;
  const __bf16* weg_bf    = wbf + 10485760;
  const __bf16* weu_bf    = wbf + 18874368;
  const __bf16* wed_bf    = wbf + 27262976;
  const __bf16* wsg_bf    = wbf + 35651584;
  const __bf16* wsu_bf    = wbf + 36700160;
  const __bf16* wsd_bf    = wbf + 37748736;

  hipMemsetAsync(cnt, 0, 256, stream);
  // 0) weights fp32 -> bf16 (once per call; ws is re-poisoned every launch)
  wconv_k<<<37888, 256, 0, stream>>>(wqkv, wdense, weg, weu, wed, wsg, wsu, wsd, wbf);
  // 1) x = rmsnorm(hidden, ln1_w) -> bf16
  rmsnorm_k<<<T_TOK, 256, 0, stream>>>(hs, ln1w, xb1);
  // 2) qkv = x @ w_qkv^T (fp32 out)
  gemm_nt<0><<<dim3(QKV_O / 128, T_TOK / 128), 256, 0, stream>>>(
      xb1, wqkv_bf, nullptr, qkv32, nullptr, nullptr, nullptr, nullptr, QKV_O, H_DIM);
  // 3) q/k norm + rope, v cast -> bf16 (b,h,s,d)
  rope_k<<<T_TOK * 6, 256, 0, stream>>>(qkv32, qlw, klw, cosp, sinp, qb, kb, vb);
  // 3b) vt = transpose(vb): [g][d][s]
  vtrans_k<<<dim3(16, 2, 8), 256, 0, stream>>>(vb, vt);
  // 4) flash attention -> outb bf16 (t, nh*hd)
  flash_k<<<dim3(S_LEN / 64, 2 * NH), 256, 0, stream>>>(qb, kb, vt, outb);
  // 5) hidden = hs + outb @ w_dense^T -> d_out (fp32)
  gemm_nt<1><<<dim3(H_DIM / 128, T_TOK / 128), 256, 0, stream>>>(
      outb, wdense_bf, nullptr, out, hs, nullptr, nullptr, nullptr, H_DIM, H_DIM);
  // 6) x2 = rmsnorm(hidden, ln2_w) -> bf16
  rmsnorm_k<<<T_TOK, 256, 0, stream>>>(out, ln2w, xb2);
  // 7) router
  router_k<<<T_TOK, 64, 0, stream>>>(out, ln2w, gw, gbias, cnt, list, wsl);
  // 8) gathered gate/up + silu-mul -> he bf16
  gemm_gateup<<<dim3(MM / 64, T_TOK / 128, 9), 256, 0, stream>>>(
      xb2, weg_bf, weu_bf, wsg_bf, wsu_bf, list, cnt, he);
  // 9) down-proj + weighted scatter-add into d_out
  gemm_nt<2><<<dim3(H_DIM / 128, T_TOK / 128, 9), 256, 0, stream>>>(
      he, wed_bf, wsd_bf, out, nullptr, list, wsl, cnt, H_DIM, MM);
}

// Round 3
// 528.348 us; speedup vs baseline: 1.1870x; 1.0376x over previous
//
#include <hip/hip_runtime.h>
#include <cstdint>
#include <cstddef>

#define T_TOK 2048
#define H_DIM 2048
#define S_LEN 1024
#define HD 128
#define NH 16
#define NKV 4
#define QKV_O 3072
#define MM 512
#define EPS 1e-6f
#define ATT_SCALE 0.08838834764831845f  // 128^-0.5

typedef __bf16 bf16x8 __attribute__((ext_vector_type(8)));
typedef __bf16 bf16x4 __attribute__((ext_vector_type(4)));
typedef float  f32x4  __attribute__((ext_vector_type(4)));

__device__ __forceinline__ __bf16 f2bf(float f) {
  unsigned u = __builtin_bit_cast(unsigned, f);
  u += 0x7fffu + ((u >> 16) & 1u);           // RNE; inputs are finite
  unsigned short h = (unsigned short)(u >> 16);
  return __builtin_bit_cast(__bf16, h);
}
__device__ __forceinline__ f32x4 fzero4() {
  f32x4 z; z[0] = 0.f; z[1] = 0.f; z[2] = 0.f; z[3] = 0.f; return z;
}
// async global->LDS, 16B per lane.
__device__ __forceinline__ void gld16(const __bf16* g, __bf16* l) {
  __builtin_amdgcn_global_load_lds(
      (const __attribute__((address_space(1))) unsigned int*)g,
      (__attribute__((address_space(3))) unsigned int*)l, 16, 0, 0);
}

// ---------------------------------------------------------------------------
// Weight fp32 -> bf16 conversion (one pass over all 8 weight tensors).
// ---------------------------------------------------------------------------
__global__ __launch_bounds__(256) void wconv_k(
    const float* __restrict__ s0, const float* __restrict__ s1,
    const float* __restrict__ s2, const float* __restrict__ s3,
    const float* __restrict__ s4, const float* __restrict__ s5,
    const float* __restrict__ s6, const float* __restrict__ s7,
    __bf16* __restrict__ dst) {
  size_t e = ((size_t)blockIdx.x * 256 + threadIdx.x) * 4;
  const size_t E0 = 6291456, E1 = 10485760, E2 = 18874368, E3 = 27262976,
               E4 = 35651584, E5 = 36700160, E6 = 37748736;
  const float* src; size_t base;
  if      (e < E0) { src = s0; base = 0;  }
  else if (e < E1) { src = s1; base = E0; }
  else if (e < E2) { src = s2; base = E1; }
  else if (e < E3) { src = s3; base = E2; }
  else if (e < E4) { src = s4; base = E3; }
  else if (e < E5) { src = s5; base = E4; }
  else if (e < E6) { src = s6; base = E5; }
  else             { src = s7; base = E6; }
  float4 f = *(const float4*)(src + (e - base));
  bf16x4 o;
  o[0] = f2bf(f.x); o[1] = f2bf(f.y); o[2] = f2bf(f.z); o[3] = f2bf(f.w);
  *(bf16x4*)(dst + e) = o;
}

// ---------------------------------------------------------------------------
// RMSNorm over H=2048, fp32 in -> bf16 out. One block (256 thr) per token.
// ---------------------------------------------------------------------------
__global__ __launch_bounds__(256) void rmsnorm_k(const float* __restrict__ X,
                                                 const float* __restrict__ W,
                                                 __bf16* __restrict__ Y) {
  int t = blockIdx.x;
  int tid = threadIdx.x, lane = tid & 63, wid = tid >> 6;
  const float4* row = (const float4*)(X + (size_t)t * H_DIM);
  float4 v0 = row[tid], v1 = row[tid + 256];
  float ss = v0.x*v0.x + v0.y*v0.y + v0.z*v0.z + v0.w*v0.w
           + v1.x*v1.x + v1.y*v1.y + v1.z*v1.z + v1.w*v1.w;
  #pragma unroll
  for (int m = 1; m <= 32; m <<= 1) ss += __shfl_xor(ss, m, 64);
  __shared__ float red[4];
  if (lane == 0) red[wid] = ss;
  __syncthreads();
  float tot = red[0] + red[1] + red[2] + red[3];
  float sc = rsqrtf(tot * (1.f / H_DIM) + EPS);
  const float4* wp = (const float4*)W;
  float4 w0 = wp[tid], w1 = wp[tid + 256];
  bf16x4 o;
  o[0] = f2bf(v0.x*w0.x*sc); o[1] = f2bf(v0.y*w0.y*sc);
  o[2] = f2bf(v0.z*w0.z*sc); o[3] = f2bf(v0.w*w0.w*sc);
  *(bf16x4*)&Y[(size_t)t*H_DIM + tid*4] = o;
  o[0] = f2bf(v1.x*w1.x*sc); o[1] = f2bf(v1.y*w1.y*sc);
  o[2] = f2bf(v1.z*w1.z*sc); o[3] = f2bf(v1.w*w1.w*sc);
  *(bf16x4*)&Y[(size_t)t*H_DIM + 1024 + tid*4] = o;
}

// ---------------------------------------------------------------------------
// NT GEMM, m97-style staging (global_load_lds 16B, XOR chunk swizzle).
// Tile 128x128, BK=64, 4 waves of 64x64, mfma 16x16x32 bf16.
// MODE 0: OB bf16 plain store (ld N)            [qkv]
// MODE 1: C fp32 = acc + resid (ld 2048)        [dense + residual]
// MODE 2: expert down-proj -> buf[t][j][:] bf16, conflict-free scatter
// ---------------------------------------------------------------------------
template<int MODE>
__global__ __launch_bounds__(256) void gemm_nt(
    const __bf16* __restrict__ A, const __bf16* __restrict__ B,
    const __bf16* __restrict__ B2, float* __restrict__ C,
    __bf16* __restrict__ OB, const float* __restrict__ resid,
    const int* __restrict__ list, const signed char* __restrict__ jsl,
    const int* __restrict__ cnt, int N, int K) {
  int e  = (MODE == 2) ? (int)blockIdx.z : 0;
  int ne = (MODE == 2) ? ((e == 8) ? T_TOK : cnt[e]) : T_TOK;
  int m0 = blockIdx.y * 128;
  if (MODE == 2 && m0 >= ne) return;
  int n0 = blockIdx.x * 128;
  const __bf16* Ab = A;
  const __bf16* Bb = B;
  if (MODE == 2) {
    Ab = A + (size_t)e * T_TOK * MM;
    Bb = (e < 8) ? B + (size_t)e * H_DIM * MM : B2;
  }
  __shared__ __bf16 sA[128 * 64];
  __shared__ __bf16 sB[128 * 64];
  int tid = threadIdx.x, lane = tid & 63, wid = tid >> 6;
  int quad = lane >> 4, l16 = lane & 15;
  int wm = wid & 1, wn = wid >> 1;

  const __bf16* gA[4]; const __bf16* gB[4];
  #pragma unroll
  for (int i = 0; i < 4; i++) {
    int p = tid + 256 * i;
    int row = p >> 3, sc = p & 7, gc = sc ^ (row & 7);
    gA[i] = Ab + (size_t)(m0 + row) * K + gc * 8;
    gB[i] = Bb + (size_t)(n0 + row) * K + gc * 8;
  }
  f32x4 acc[4][4];
  #pragma unroll
  for (int i = 0; i < 4; i++)
    #pragma unroll
    for (int j = 0; j < 4; j++) acc[i][j] = fzero4();

  for (int k0 = 0; k0 < K; k0 += 64) {
    __syncthreads();
    #pragma unroll
    for (int i = 0; i < 4; i++) {
      gld16(gA[i] + k0, &sA[(tid + 256 * i) * 8]);
      gld16(gB[i] + k0, &sB[(tid + 256 * i) * 8]);
    }
    __syncthreads();
    #pragma unroll
    for (int ks = 0; ks < 64; ks += 32) {
      int cb = ks >> 3;  // chunk base: 0 or 4
      bf16x8 aF[4], bF[4];
      #pragma unroll
      for (int mt = 0; mt < 4; mt++) {
        int row = wm * 64 + mt * 16 + l16;
        int pos = row * 8 + ((cb + quad) ^ (row & 7));
        aF[mt] = *(const bf16x8*)&sA[pos * 8];
      }
      #pragma unroll
      for (int nt = 0; nt < 4; nt++) {
        int row = wn * 64 + nt * 16 + l16;
        int pos = row * 8 + ((cb + quad) ^ (row & 7));
        bF[nt] = *(const bf16x8*)&sB[pos * 8];
      }
      #pragma unroll
      for (int mt = 0; mt < 4; mt++)
        #pragma unroll
        for (int nt = 0; nt < 4; nt++)
          acc[mt][nt] = __builtin_amdgcn_mfma_f32_16x16x32_bf16(
              aF[mt], bF[nt], acc[mt][nt], 0, 0, 0);
    }
  }
  // Epilogue. C-layout: row = quad*4+reg, col = lane&15 (m89-verified).
  #pragma unroll
  for (int mt = 0; mt < 4; mt++) {
    #pragma unroll
    for (int nt = 0; nt < 4; nt++) {
      #pragma unroll
      for (int r = 0; r < 4; r++) {
        int row_l = wm*64 + mt*16 + quad*4 + r;
        int col_l = wn*64 + nt*16 + l16;
        int grow = m0 + row_l, gcol = n0 + col_l;
        float val = acc[mt][nt][r];
        if (MODE == 0) {
          OB[(size_t)grow * N + gcol] = f2bf(val);
        } else if (MODE == 1) {
          C[(size_t)grow * H_DIM + gcol] = val + resid[(size_t)grow * H_DIM + gcol];
        } else {
          if (grow < ne) {
            int tk = list[e * T_TOK + grow];
            int j  = (e == 8) ? 2 : (int)jsl[e * T_TOK + grow];
            OB[((size_t)tk * 3 + j) * H_DIM + gcol] = f2bf(val);
          }
        }
      }
    }
  }
}

// ---------------------------------------------------------------------------
// Combine: out[t] += buf[t][0] + buf[t][1] + buf[t][2]  (bf16 contributions).
// ---------------------------------------------------------------------------
__global__ __launch_bounds__(256) void combine_k(const __bf16* __restrict__ buf,
                                                 float* __restrict__ out) {
  int t = blockIdx.x, tid = threadIdx.x;
  const __bf16* base = buf + (size_t)t * 3 * H_DIM;
  bf16x8 v0 = *(const bf16x8*)(base + tid * 8);
  bf16x8 v1 = *(const bf16x8*)(base + H_DIM + tid * 8);
  bf16x8 v2 = *(const bf16x8*)(base + 2 * H_DIM + tid * 8);
  float* o = out + (size_t)t * H_DIM + tid * 8;
  float4 a = *(float4*)o, b = *(float4*)(o + 4);
  a.x += (float)v0[0] + (float)v1[0] + (float)v2[0];
  a.y += (float)v0[1] + (float)v1[1] + (float)v2[1];
  a.z += (float)v0[2] + (float)v1[2] + (float)v2[2];
  a.w += (float)v0[3] + (float)v1[3] + (float)v2[3];
  b.x += (float)v0[4] + (float)v1[4] + (float)v2[4];
  b.y += (float)v0[5] + (float)v1[5] + (float)v2[5];
  b.z += (float)v0[6] + (float)v1[6] + (float)v2[6];
  b.w += (float)v0[7] + (float)v1[7] + (float)v2[7];
  *(float4*)o = a; *(float4*)(o + 4) = b;
}

// ---------------------------------------------------------------------------
// Per (token, head): q/k RMSNorm (HD=128) + RoPE, v passthrough; bf16 in/out.
// 256-thread blocks = 4 heads; wave handles one head, lane d holds d, d+64.
// ---------------------------------------------------------------------------
__global__ __launch_bounds__(256) void rope_k(
    const __bf16* __restrict__ qkv, const float* __restrict__ qlw,
    const float* __restrict__ klw, const float* __restrict__ cosp,
    const float* __restrict__ sinp, __bf16* __restrict__ qb,
    __bf16* __restrict__ kb, __bf16* __restrict__ vb) {
  int bid = blockIdx.x;                 // T_TOK * 6
  int t = bid / 6;
  int head = (bid % 6) * 4 + (threadIdx.x >> 6);
  int b = t >> 10, s = t & 1023;
  int d = threadIdx.x & 63;
  const __bf16* src = qkv + (size_t)t * QKV_O + head * HD;
  float x1 = (float)src[d], x2 = (float)src[d + 64];
  if (head < 20) {
    float ssq = x1*x1 + x2*x2;
    #pragma unroll
    for (int m = 1; m <= 32; m <<= 1) ssq += __shfl_xor(ssq, m, 64);
    float sc = rsqrtf(ssq * (1.f / HD) + EPS);
    const float* w = (head < 16) ? qlw : klw;
    x1 = x1 * sc * w[d];
    x2 = x2 * sc * w[d + 64];
    size_t cb = (size_t)t * HD;
    float c1 = cosp[cb + d], s1 = sinp[cb + d];
    float c2 = cosp[cb + d + 64], s2 = sinp[cb + d + 64];
    float o1 = x1 * c1 - x2 * s1;
    float o2 = x2 * c2 + x1 * s2;
    if (head < 16) {
      __bf16* dst = qb + (((size_t)(b * NH + head)) * S_LEN + s) * HD;
      dst[d] = f2bf(o1); dst[d + 64] = f2bf(o2);
    } else {
      int kv = head - 16;
      __bf16* dst = kb + (((size_t)(b * NKV + kv)) * S_LEN + s) * HD;
      dst[d] = f2bf(o1); dst[d + 64] = f2bf(o2);
    }
  } else {
    int kv = head - 20;
    __bf16* dst = vb + (((size_t)(b * NKV + kv)) * S_LEN + s) * HD;
    dst[d] = src[d]; dst[d + 64] = src[d + 64];
  }
}

// ---------------------------------------------------------------------------
// V transpose: vb [g][s][d] -> vt [g][d][s]  (g = b*NKV+kv), 64x64 tiles.
// ---------------------------------------------------------------------------
__global__ __launch_bounds__(256) void vtrans_k(const __bf16* __restrict__ vb,
                                                __bf16* __restrict__ vt) {
  int s0 = blockIdx.x * 64, d0 = blockIdx.y * 64, g = blockIdx.z;
  __shared__ __bf16 sT[64 * 80];
  int tid = threadIdx.x;
  const __bf16* src = vb + (size_t)g * S_LEN * HD;
  #pragma unroll
  for (int i = 0; i < 2; i++) {
    int p = tid + 256 * i;
    int rs = p >> 3, cc = p & 7;
    bf16x8 v = *(const bf16x8*)(src + (size_t)(s0 + rs) * HD + d0 + cc * 8);
    #pragma unroll
    for (int j = 0; j < 8; j++) sT[(cc * 8 + j) * 80 + rs] = v[j];
  }
  __syncthreads();
  __bf16* dst = vt + (size_t)g * HD * S_LEN;
  #pragma unroll
  for (int i = 0; i < 2; i++) {
    int p = tid + 256 * i;
    int rd = p >> 3, cs = p & 7;
    bf16x8 v = *(const bf16x8*)&sT[rd * 80 + cs * 8];
    *(bf16x8*)(dst + (size_t)(d0 + rd) * S_LEN + s0 + cs * 8) = v;
  }
}

// ---------------------------------------------------------------------------
// Flash attention v2. 64-row Q tile, 64-col K/V tiles, global_load_lds
// staging with XOR swizzle, Vt pre-transposed globally, sP unioned onto sK.
// LDS = 48KB -> 3 blocks/CU.
// ---------------------------------------------------------------------------
__global__ __launch_bounds__(256) void flash_k(
    const __bf16* __restrict__ qb, const __bf16* __restrict__ kb,
    const __bf16* __restrict__ vt, __bf16* __restrict__ outb) {
  int qt = blockIdx.x, bh = blockIdx.y;
  int b = bh >> 4, h = bh & 15, kv = h >> 2;
  int tid = threadIdx.x, lane = tid & 63, wid = tid >> 6;
  int quad = lane >> 4, l16 = lane & 15;
  __shared__ __bf16 sQ[64 * 128];
  __shared__ __bf16 sKP[64 * 128];      // sK; reused as sP (64*72) after (c)
  __shared__ __bf16 sVt[128 * 64];
  __bf16* sK = sKP;
  __bf16* sP = sKP;

  const __bf16* qsrc = qb + (((size_t)(b * NH + h)) * S_LEN + qt * 64) * HD;
  #pragma unroll
  for (int i = 0; i < 4; i++) {
    int p = tid + 256 * i;
    int row = p >> 4, sc = p & 15, gc = sc ^ (row & 7);
    gld16(qsrc + (size_t)row * HD + gc * 8, &sQ[p * 8]);
  }
  const __bf16* kbase  = kb + ((size_t)(b * NKV + kv)) * S_LEN * HD;
  const __bf16* vtbase = vt + ((size_t)(b * NKV + kv)) * HD * S_LEN;
  const __bf16* gK[4]; const __bf16* gV[4];
  #pragma unroll
  for (int i = 0; i < 4; i++) {
    int p = tid + 256 * i;
    int rowk = p >> 4, sck = p & 15, gck = sck ^ (rowk & 7);
    gK[i] = kbase + (size_t)rowk * HD + gck * 8;
    int rowv = p >> 3, scv = p & 7, gcv = scv ^ (rowv & 7);
    gV[i] = vtbase + (size_t)rowv * S_LEN + gcv * 8;
  }
  float mrow[4], lrow[4];
  #pragma unroll
  for (int r = 0; r < 4; r++) { mrow[r] = -__builtin_inff(); lrow[r] = 0.f; }
  f32x4 accO[8];
  #pragma unroll
  for (int i = 0; i < 8; i++) accO[i] = fzero4();

  for (int kt = 0; kt < 16; kt++) {
    __syncthreads();                         // (a) prev PV done (also Q drain)
    #pragma unroll
    for (int i = 0; i < 4; i++) {
      gld16(gK[i] + (size_t)kt * 64 * HD, &sK[(tid + 256 * i) * 8]);
      gld16(gV[i] + kt * 64, &sVt[(tid + 256 * i) * 8]);
    }
    __syncthreads();                         // (b) staging visible
    f32x4 accS[4];
    #pragma unroll
    for (int jt = 0; jt < 4; jt++) accS[jt] = fzero4();
    int rowA = wid * 16 + l16;
    #pragma unroll
    for (int ks2 = 0; ks2 < 4; ks2++) {
      int posA = rowA * 16 + ((ks2 * 4 + quad) ^ (rowA & 7));
      bf16x8 aF = *(const bf16x8*)&sQ[posA * 8];
      #pragma unroll
      for (int jt = 0; jt < 4; jt++) {
        int rowB = jt * 16 + l16;
        int posB = rowB * 16 + ((ks2 * 4 + quad) ^ (rowB & 7));
        bf16x8 bF = *(const bf16x8*)&sK[posB * 8];
        accS[jt] = __builtin_amdgcn_mfma_f32_16x16x32_bf16(aF, bF, accS[jt], 0, 0, 0);
      }
    }
    float alpha[4];
    #pragma unroll
    for (int r = 0; r < 4; r++) {
      float mx = -__builtin_inff();
      #pragma unroll
      for (int jt = 0; jt < 4; jt++) {
        accS[jt][r] *= ATT_SCALE;
        mx = fmaxf(mx, accS[jt][r]);
      }
      #pragma unroll
      for (int m = 1; m <= 8; m <<= 1) mx = fmaxf(mx, __shfl_xor(mx, m, 64));
      float mn = fmaxf(mrow[r], mx);
      float al = __expf(mrow[r] - mn);
      float rs = 0.f;
      #pragma unroll
      for (int jt = 0; jt < 4; jt++) {
        float p = __expf(accS[jt][r] - mn);
        accS[jt][r] = p;
        rs += p;
      }
      #pragma unroll
      for (int m = 1; m <= 8; m <<= 1) rs += __shfl_xor(rs, m, 64);
      lrow[r] = lrow[r] * al + rs;
      mrow[r] = mn;
      alpha[r] = al;
    }
    #pragma unroll
    for (int nt = 0; nt < 8; nt++)
      #pragma unroll
      for (int r = 0; r < 4; r++) accO[nt][r] *= alpha[r];
    __syncthreads();                         // (c) all waves done reading sK
    #pragma unroll
    for (int jt = 0; jt < 4; jt++)
      #pragma unroll
      for (int r = 0; r < 4; r++)
        sP[(wid * 16 + quad * 4 + r) * 72 + jt * 16 + l16] = f2bf(accS[jt][r]);
    __syncthreads();                         // (d) sP visible
    #pragma unroll
    for (int ks2 = 0; ks2 < 2; ks2++) {
      bf16x8 aF = *(const bf16x8*)&sP[(wid * 16 + l16) * 72 + ks2 * 32 + quad * 8];
      #pragma unroll
      for (int nt = 0; nt < 8; nt++) {
        int rowB = nt * 16 + l16;
        int posB = rowB * 8 + ((ks2 * 4 + quad) ^ (rowB & 7));
        bf16x8 bF = *(const bf16x8*)&sVt[posB * 8];
        accO[nt] = __builtin_amdgcn_mfma_f32_16x16x32_bf16(aF, bF, accO[nt], 0, 0, 0);
      }
    }
  }
  #pragma unroll
  for (int nt = 0; nt < 8; nt++) {
    #pragma unroll
    for (int r = 0; r < 4; r++) {
      int srow = qt * 64 + wid * 16 + quad * 4 + r;
      float val = accO[nt][r] / lrow[r];
      outb[((size_t)(b * S_LEN + srow)) * H_DIM + h * HD + nt * 16 + l16] = f2bf(val);
    }
  }
}

// ---------------------------------------------------------------------------
// Router: also records jsl (which of the token's 2 contribution slots).
// ---------------------------------------------------------------------------
__global__ __launch_bounds__(64) void router_k(
    const float* __restrict__ hid, const float* __restrict__ ln2w,
    const float* __restrict__ gw, const float* __restrict__ gb,
    int* __restrict__ cnt, int* __restrict__ list, float* __restrict__ wsl,
    signed char* __restrict__ jsl) {
  int t = blockIdx.x;
  int lane = threadIdx.x;
  const float* xr = hid + (size_t)t * H_DIM;
  float x[32];
  float ss = 0.f;
  #pragma unroll
  for (int j = 0; j < 32; j++) { x[j] = xr[j * 64 + lane]; ss += x[j] * x[j]; }
  #pragma unroll
  for (int m = 1; m <= 32; m <<= 1) ss += __shfl_xor(ss, m, 64);
  float sc = rsqrtf(ss * (1.f / H_DIM) + EPS);
  float xn[32];
  #pragma unroll
  for (int j = 0; j < 32; j++) xn[j] = x[j] * sc * ln2w[j * 64 + lane];
  float lg[8];
  #pragma unroll
  for (int e = 0; e < 8; e++) {
    float d = 0.f;
    #pragma unroll
    for (int j = 0; j < 32; j++) d += xn[j] * gw[(size_t)e * H_DIM + j * 64 + lane];
    #pragma unroll
    for (int m = 1; m <= 32; m <<= 1) d += __shfl_xor(d, m, 64);
    lg[e] = d;
  }
  float s[8], sb[8];
  #pragma unroll
  for (int e = 0; e < 8; e++) {
    s[e] = 1.f / (1.f + __expf(-lg[e]));
    sb[e] = s[e] + gb[e];
  }
  float gs[4];
  #pragma unroll
  for (int g = 0; g < 4; g++) gs[g] = sb[2 * g] + sb[2 * g + 1];
  int g1 = 0;
  for (int g = 1; g < 4; g++) if (gs[g] > gs[g1]) g1 = g;
  int g2 = -1;
  for (int g = 0; g < 4; g++) if (g != g1 && (g2 < 0 || gs[g] > gs[g2])) g2 = g;
  unsigned emask = (3u << (2 * g1)) | (3u << (2 * g2));
  int e1 = -1;
  for (int e = 0; e < 8; e++) if (((emask >> e) & 1u) && (e1 < 0 || sb[e] > sb[e1])) e1 = e;
  int e2 = -1;
  for (int e = 0; e < 8; e++) if (((emask >> e) & 1u) && e != e1 && (e2 < 0 || sb[e] > sb[e2])) e2 = e;
  float w1 = s[e1], w2 = s[e2];
  float dn = w1 + w2 + 1e-20f;
  w1 /= dn; w2 /= dn;   // RSF = 1.0
  if (lane == 0) {
    int p1 = atomicAdd(&cnt[e1], 1);
    list[e1 * T_TOK + p1] = t; wsl[e1 * T_TOK + p1] = w1; jsl[e1 * T_TOK + p1] = 0;
    int p2 = atomicAdd(&cnt[e2], 1);
    list[e2 * T_TOK + p2] = t; wsl[e2 * T_TOK + p2] = w2; jsl[e2 * T_TOK + p2] = 1;
    list[8 * T_TOK + t] = t; wsl[8 * T_TOK + t] = 1.f;   // shared expert
  }
}

// ---------------------------------------------------------------------------
// Gathered gate+up GEMM with fused silu-mul and routing-weight fold.
// Tile 128(M) x 64(N), BK=64; wave w owns rows [32w, 32w+32).
// ---------------------------------------------------------------------------
__global__ __launch_bounds__(256) void gemm_gateup(
    const __bf16* __restrict__ X, const __bf16* __restrict__ weg,
    const __bf16* __restrict__ weu, const __bf16* __restrict__ wsg,
    const __bf16* __restrict__ wsu, const int* __restrict__ list,
    const float* __restrict__ wsl, const int* __restrict__ cnt,
    __bf16* __restrict__ he) {
  int e = blockIdx.z;
  int ne = (e == 8) ? T_TOK : cnt[e];
  int m0 = blockIdx.y * 128;
  if (m0 >= ne) return;
  int n0 = blockIdx.x * 64;
  const __bf16* bg = (e < 8) ? weg + (size_t)e * MM * H_DIM : wsg;
  const __bf16* bu = (e < 8) ? weu + (size_t)e * MM * H_DIM : wsu;
  const int* lst = list + e * T_TOK;
  __shared__ __bf16 sA[128 * 64];
  __shared__ __bf16 sBg[64 * 64];
  __shared__ __bf16 sBu[64 * 64];
  int tid = threadIdx.x, lane = tid & 63, wid = tid >> 6;
  int quad = lane >> 4, l16 = lane & 15;

  const __bf16* gA[4]; const __bf16* gBg[2]; const __bf16* gBu[2];
  #pragma unroll
  for (int i = 0; i < 4; i++) {
    int p = tid + 256 * i;
    int row = p >> 3, sc = p & 7, gc = sc ^ (row & 7);
    int r = m0 + row; if (r >= ne) r = ne - 1;
    int tk = lst[r];
    gA[i] = X + (size_t)tk * H_DIM + gc * 8;
  }
  #pragma unroll
  for (int i = 0; i < 2; i++) {
    int p = tid + 256 * i;
    int row = p >> 3, sc = p & 7, gc = sc ^ (row & 7);
    gBg[i] = bg + (size_t)(n0 + row) * H_DIM + gc * 8;
    gBu[i] = bu + (size_t)(n0 + row) * H_DIM + gc * 8;
  }
  f32x4 ag[2][4], au[2][4];
  #pragma unroll
  for (int i = 0; i < 2; i++)
    #pragma unroll
    for (int j = 0; j < 4; j++) { ag[i][j] = fzero4(); au[i][j] = fzero4(); }

  for (int k0 = 0; k0 < H_DIM; k0 += 64) {
    __syncthreads();
    #pragma unroll
    for (int i = 0; i < 4; i++)
      gld16(gA[i] + k0, &sA[(tid + 256 * i) * 8]);
    #pragma unroll
    for (int i = 0; i < 2; i++) {
      gld16(gBg[i] + k0, &sBg[(tid + 256 * i) * 8]);
      gld16(gBu[i] + k0, &sBu[(tid + 256 * i) * 8]);
    }
    __syncthreads();
    #pragma unroll
    for (int ks = 0; ks < 64; ks += 32) {
      int cb = ks >> 3;
      bf16x8 aF[2], gF[4], uF[4];
      #pragma unroll
      for (int mt = 0; mt < 2; mt++) {
        int row = wid * 32 + mt * 16 + l16;
        int pos = row * 8 + ((cb + quad) ^ (row & 7));
        aF[mt] = *(const bf16x8*)&sA[pos * 8];
      }
      #pragma unroll
      for (int nt = 0; nt < 4; nt++) {
        int row = nt * 16 + l16;
        int pos = row * 8 + ((cb + quad) ^ (row & 7));
        gF[nt] = *(const bf16x8*)&sBg[pos * 8];
        uF[nt] = *(const bf16x8*)&sBu[pos * 8];
      }
      #pragma unroll
      for (int mt = 0; mt < 2; mt++)
        #pragma unroll
        for (int nt = 0; nt < 4; nt++) {
          ag[mt][nt] = __builtin_amdgcn_mfma_f32_16x16x32_bf16(aF[mt], gF[nt], ag[mt][nt], 0, 0, 0);
          au[mt][nt] = __builtin_amdgcn_mfma_f32_16x16x32_bf16(aF[mt], uF[nt], au[mt][nt], 0, 0, 0);
        }
    }
  }
  #pragma unroll
  for (int mt = 0; mt < 2; mt++) {
    #pragma unroll
    for (int nt = 0; nt < 4; nt++) {
      #pragma unroll
      for (int r = 0; r < 4; r++) {
        int row_l = wid * 32 + mt * 16 + quad * 4 + r;
        int grow = m0 + row_l;
        if (grow < ne) {
          float g = ag[mt][nt][r], u = au[mt][nt][r];
          float hv = g / (1.f + __expf(-g)) * u;     // silu(g)*u
          hv *= wsl[e * T_TOK + grow];               // fold routing weight
          he[((size_t)e * T_TOK + grow) * MM + n0 + nt * 16 + l16] = f2bf(hv);
        }
      }
    }
  }
}

// ---------------------------------------------------------------------------
extern "C" void kernel_launch(void* const* d_in, const int* in_sizes, int n_in,
                              void* d_out, int out_size, void* d_ws, size_t ws_size,
                              hipStream_t stream) {
  (void)in_sizes; (void)n_in; (void)out_size; (void)ws_size;
  const float* hs     = (const float*)d_in[0];
  const float* cosp   = (const float*)d_in[1];
  const float* sinp   = (const float*)d_in[2];
  const float* ln1w   = (const float*)d_in[3];
  const float* wqkv   = (const float*)d_in[4];
  const float* qlw    = (const float*)d_in[5];
  const float* klw    = (const float*)d_in[6];
  const float* wdense = (const float*)d_in[7];
  const float* ln2w   = (const float*)d_in[8];
  const float* gw     = (const float*)d_in[9];
  const float* gbias  = (const float*)d_in[10];
  const float* weg    = (const float*)d_in[11];
  const float* weu    = (const float*)d_in[12];
  const float* wed    = (const float*)d_in[13];
  const float* wsg    = (const float*)d_in[14];
  const float* wsu    = (const float*)d_in[15];
  const float* wsd    = (const float*)d_in[16];
  float* out = (float*)d_out;

  char* ws = (char*)d_ws;
  size_t off = 0;
  auto alloc = [&](size_t b) { char* p = ws + off; off += (b + 255) & ~(size_t)255; return p; };
  __bf16* wbf   = (__bf16*)alloc((size_t)38797312 * 2);               // 74 MB
  __bf16* xb1   = (__bf16*)alloc((size_t)T_TOK * H_DIM * 2);
  __bf16* qreg  = (__bf16*)alloc((size_t)T_TOK * 3 * H_DIM * 2);      // qkv bf16 / buf
  __bf16* qb    = (__bf16*)alloc((size_t)2 * NH  * S_LEN * HD * 2);   // he span start
  __bf16* kb    = (__bf16*)alloc((size_t)2 * NKV * S_LEN * HD * 2);
  __bf16* vb    = (__bf16*)alloc((size_t)2 * NKV * S_LEN * HD * 2);
  __bf16* vt    = (__bf16*)alloc((size_t)2 * NKV * S_LEN * HD * 2);
  __bf16* outb  = (__bf16*)alloc((size_t)T_TOK * H_DIM * 2);
  __bf16* xb2   = (__bf16*)alloc((size_t)T_TOK * H_DIM * 2);
  int*    cnt   = (int*)   alloc(256);
  int*    list  = (int*)   alloc((size_t)9 * T_TOK * 4);
  float*  wsl   = (float*) alloc((size_t)9 * T_TOK * 4);
  signed char* jsl = (signed char*)alloc((size_t)9 * T_TOK);
  __bf16* qkvb  = qreg;            // [T, 3072] bf16 (dead after rope)
  __bf16* buf   = qreg;            // [T][3][H] bf16 contribs (exact same size)
  __bf16* he    = qb;              // 18.9 MB over dead qb..outb span (23 MB)

  const __bf16* wqkv_bf   = wbf;
  const __bf16* wdense_bf = wbf + 6291456;
  const __bf16* weg_bf    = wbf + 10485760;
  const __bf16* weu_bf    = wbf + 18874368;
  const __bf16* wed_bf    = wbf + 27262976;
  const __bf16* wsg_bf    = wbf + 35651584;
  const __bf16* wsu_bf    = wbf + 36700160;
  const __bf16* wsd_bf    = wbf + 37748736;

  hipMemsetAsync(cnt, 0, 256, stream);
  // 0) weights fp32 -> bf16
  wconv_k<<<37888, 256, 0, stream>>>(wqkv, wdense, weg, weu, wed, wsg, wsu, wsd, wbf);
  // 1) x = rmsnorm(hidden, ln1_w) -> bf16
  rmsnorm_k<<<T_TOK, 256, 0, stream>>>(hs, ln1w, xb1);
  // 2) qkv = x @ w_qkv^T (bf16 out)
  gemm_nt<0><<<dim3(QKV_O / 128, T_TOK / 128), 256, 0, stream>>>(
      xb1, wqkv_bf, nullptr, nullptr, qkvb, nullptr, nullptr, nullptr, nullptr, QKV_O, H_DIM);
  // 3) q/k norm + rope, v -> bf16 (b,h,s,d)
  rope_k<<<T_TOK * 6, 256, 0, stream>>>(qkvb, qlw, klw, cosp, sinp, qb, kb, vb);
  // 3b) vt = transpose(vb): [g][d][s]
  vtrans_k<<<dim3(16, 2, 8), 256, 0, stream>>>(vb, vt);
  // 4) flash attention -> outb bf16 (t, nh*hd)
  flash_k<<<dim3(S_LEN / 64, 2 * NH), 256, 0, stream>>>(qb, kb, vt, outb);
  // 5) hidden = hs + outb @ w_dense^T -> d_out (fp32)
  gemm_nt<1><<<dim3(H_DIM / 128, T_TOK / 128), 256, 0, stream>>>(
      outb, wdense_bf, nullptr, out, nullptr, hs, nullptr, nullptr, nullptr, H_DIM, H_DIM);
  // 6) x2 = rmsnorm(hidden, ln2_w) -> bf16
  rmsnorm_k<<<T_TOK, 256, 0, stream>>>(out, ln2w, xb2);
  // 7) router (writes list/wsl/jsl)
  router_k<<<T_TOK, 64, 0, stream>>>(out, ln2w, gw, gbias, cnt, list, wsl, jsl);
  // 8) gathered gate/up + silu-mul + weight fold -> he bf16
  gemm_gateup<<<dim3(MM / 64, T_TOK / 128, 9), 256, 0, stream>>>(
      xb2, weg_bf, weu_bf, wsg_bf, wsu_bf, list, wsl, cnt, he);
  // 9) down-proj -> buf[t][j][:] (conflict-free bf16 stores, no atomics)
  gemm_nt<2><<<dim3(H_DIM / 128, T_TOK / 128, 9), 256, 0, stream>>>(
      he, wed_bf, wsd_bf, nullptr, buf, nullptr, list, jsl, cnt, H_DIM, MM);
  // 10) out[t] += buf[t][0] + buf[t][1] + buf[t][2]
  combine_k<<<T_TOK, 256, 0, stream>>>(buf, out);
}

// Round 4
// 526.533 us; speedup vs baseline: 1.1911x; 1.0034x over previous
//
#include <hip/hip_runtime.h>
#include <cstdint>
#include <cstddef>

#define T_TOK 2048
#define H_DIM 2048
#define S_LEN 1024
#define HD 128
#define NH 16
#define NKV 4
#define QKV_O 3072
#define MM 512
#define EPS 1e-6f
#define ATT_SCALE 0.08838834764831845f  // 128^-0.5

typedef __bf16 bf16x8 __attribute__((ext_vector_type(8)));
typedef __bf16 bf16x4 __attribute__((ext_vector_type(4)));
typedef float  f32x4  __attribute__((ext_vector_type(4)));

__device__ __forceinline__ __bf16 f2bf(float f) {
  unsigned u = __builtin_bit_cast(unsigned, f);
  u += 0x7fffu + ((u >> 16) & 1u);           // RNE; inputs are finite
  unsigned short h = (unsigned short)(u >> 16);
  return __builtin_bit_cast(__bf16, h);
}
__device__ __forceinline__ f32x4 fzero4() {
  f32x4 z; z[0] = 0.f; z[1] = 0.f; z[2] = 0.f; z[3] = 0.f; return z;
}
// async global->LDS, 16B per lane.
__device__ __forceinline__ void gld16(const __bf16* g, __bf16* l) {
  __builtin_amdgcn_global_load_lds(
      (const __attribute__((address_space(1))) unsigned int*)g,
      (__attribute__((address_space(3))) unsigned int*)l, 16, 0, 0);
}

// ---------------------------------------------------------------------------
// Weight fp32 -> bf16 conversion. 8 elements/thread (32B read, 16B write).
// ---------------------------------------------------------------------------
__global__ __launch_bounds__(256) void wconv_k(
    const float* __restrict__ s0, const float* __restrict__ s1,
    const float* __restrict__ s2, const float* __restrict__ s3,
    const float* __restrict__ s4, const float* __restrict__ s5,
    const float* __restrict__ s6, const float* __restrict__ s7,
    __bf16* __restrict__ dst) {
  size_t e = ((size_t)blockIdx.x * 256 + threadIdx.x) * 8;
  const size_t E0 = 6291456, E1 = 10485760, E2 = 18874368, E3 = 27262976,
               E4 = 35651584, E5 = 36700160, E6 = 37748736;
  const float* src; size_t base;
  if      (e < E0) { src = s0; base = 0;  }
  else if (e < E1) { src = s1; base = E0; }
  else if (e < E2) { src = s2; base = E1; }
  else if (e < E3) { src = s3; base = E2; }
  else if (e < E4) { src = s4; base = E3; }
  else if (e < E5) { src = s5; base = E4; }
  else if (e < E6) { src = s6; base = E5; }
  else             { src = s7; base = E6; }
  const float4* sp = (const float4*)(src + (e - base));
  float4 f0 = sp[0], f1 = sp[1];
  bf16x8 o;
  o[0] = f2bf(f0.x); o[1] = f2bf(f0.y); o[2] = f2bf(f0.z); o[3] = f2bf(f0.w);
  o[4] = f2bf(f1.x); o[5] = f2bf(f1.y); o[6] = f2bf(f1.z); o[7] = f2bf(f1.w);
  *(bf16x8*)(dst + e) = o;
}

// ---------------------------------------------------------------------------
// RMSNorm over H=2048, fp32 in -> bf16 out. One block (256 thr) per token.
// ---------------------------------------------------------------------------
__global__ __launch_bounds__(256) void rmsnorm_k(const float* __restrict__ X,
                                                 const float* __restrict__ W,
                                                 __bf16* __restrict__ Y) {
  int t = blockIdx.x;
  int tid = threadIdx.x, lane = tid & 63, wid = tid >> 6;
  const float4* row = (const float4*)(X + (size_t)t * H_DIM);
  float4 v0 = row[tid], v1 = row[tid + 256];
  float ss = v0.x*v0.x + v0.y*v0.y + v0.z*v0.z + v0.w*v0.w
           + v1.x*v1.x + v1.y*v1.y + v1.z*v1.z + v1.w*v1.w;
  #pragma unroll
  for (int m = 1; m <= 32; m <<= 1) ss += __shfl_xor(ss, m, 64);
  __shared__ float red[4];
  if (lane == 0) red[wid] = ss;
  __syncthreads();
  float tot = red[0] + red[1] + red[2] + red[3];
  float sc = rsqrtf(tot * (1.f / H_DIM) + EPS);
  const float4* wp = (const float4*)W;
  float4 w0 = wp[tid], w1 = wp[tid + 256];
  bf16x4 o;
  o[0] = f2bf(v0.x*w0.x*sc); o[1] = f2bf(v0.y*w0.y*sc);
  o[2] = f2bf(v0.z*w0.z*sc); o[3] = f2bf(v0.w*w0.w*sc);
  *(bf16x4*)&Y[(size_t)t*H_DIM + tid*4] = o;
  o[0] = f2bf(v1.x*w1.x*sc); o[1] = f2bf(v1.y*w1.y*sc);
  o[2] = f2bf(v1.z*w1.z*sc); o[3] = f2bf(v1.w*w1.w*sc);
  *(bf16x4*)&Y[(size_t)t*H_DIM + 1024 + tid*4] = o;
}

// ---------------------------------------------------------------------------
// NT GEMM, m97-style staging + double-buffered LDS (one barrier per K-iter;
// prefetch of tile k+1 overlaps MFMA on tile k).
// Tile 128x128, BK=64, 4 waves of 64x64, mfma 16x16x32 bf16.
// MODE 0: OB bf16 plain store (ld N)            [qkv]
// MODE 1: C fp32 = acc + resid (ld 2048)        [dense + residual]
// MODE 2: expert down-proj -> buf[t][j][:] bf16, conflict-free scatter
// ---------------------------------------------------------------------------
template<int MODE>
__global__ __launch_bounds__(256) void gemm_nt(
    const __bf16* __restrict__ A, const __bf16* __restrict__ B,
    const __bf16* __restrict__ B2, float* __restrict__ C,
    __bf16* __restrict__ OB, const float* __restrict__ resid,
    const int* __restrict__ list, const signed char* __restrict__ jsl,
    const int* __restrict__ cnt, int N, int K) {
  int e  = (MODE == 2) ? (int)blockIdx.z : 0;
  int ne = (MODE == 2) ? ((e == 8) ? T_TOK : cnt[e]) : T_TOK;
  int m0 = blockIdx.y * 128;
  if (MODE == 2 && m0 >= ne) return;
  int n0 = blockIdx.x * 128;
  const __bf16* Ab = A;
  const __bf16* Bb = B;
  if (MODE == 2) {
    Ab = A + (size_t)e * T_TOK * MM;
    Bb = (e < 8) ? B + (size_t)e * H_DIM * MM : B2;
  }
  __shared__ __bf16 sA[2][128 * 64];
  __shared__ __bf16 sB[2][128 * 64];
  int tid = threadIdx.x, lane = tid & 63, wid = tid >> 6;
  int quad = lane >> 4, l16 = lane & 15;
  int wm = wid & 1, wn = wid >> 1;

  const __bf16* gA[4]; const __bf16* gB[4];
  #pragma unroll
  for (int i = 0; i < 4; i++) {
    int p = tid + 256 * i;
    int row = p >> 3, sc = p & 7, gc = sc ^ (row & 7);
    gA[i] = Ab + (size_t)(m0 + row) * K + gc * 8;
    gB[i] = Bb + (size_t)(n0 + row) * K + gc * 8;
  }
  f32x4 acc[4][4];
  #pragma unroll
  for (int i = 0; i < 4; i++)
    #pragma unroll
    for (int j = 0; j < 4; j++) acc[i][j] = fzero4();

  auto stage = [&](int buf, int k0) {
    #pragma unroll
    for (int i = 0; i < 4; i++) {
      gld16(gA[i] + k0, &sA[buf][(tid + 256 * i) * 8]);
      gld16(gB[i] + k0, &sB[buf][(tid + 256 * i) * 8]);
    }
  };
  stage(0, 0);
  int cur = 0;
  for (int k0 = 0; k0 < K; k0 += 64) {
    __syncthreads();                        // cur staged; prev compute done
    if (k0 + 64 < K) stage(cur ^ 1, k0 + 64);
    #pragma unroll
    for (int ks = 0; ks < 64; ks += 32) {
      int cb = ks >> 3;  // chunk base: 0 or 4
      bf16x8 aF[4], bF[4];
      #pragma unroll
      for (int mt = 0; mt < 4; mt++) {
        int row = wm * 64 + mt * 16 + l16;
        int pos = row * 8 + ((cb + quad) ^ (row & 7));
        aF[mt] = *(const bf16x8*)&sA[cur][pos * 8];
      }
      #pragma unroll
      for (int nt = 0; nt < 4; nt++) {
        int row = wn * 64 + nt * 16 + l16;
        int pos = row * 8 + ((cb + quad) ^ (row & 7));
        bF[nt] = *(const bf16x8*)&sB[cur][pos * 8];
      }
      #pragma unroll
      for (int mt = 0; mt < 4; mt++)
        #pragma unroll
        for (int nt = 0; nt < 4; nt++)
          acc[mt][nt] = __builtin_amdgcn_mfma_f32_16x16x32_bf16(
              aF[mt], bF[nt], acc[mt][nt], 0, 0, 0);
    }
    cur ^= 1;
  }
  // Epilogue. C-layout: row = quad*4+reg, col = lane&15 (m89-verified).
  #pragma unroll
  for (int mt = 0; mt < 4; mt++) {
    #pragma unroll
    for (int nt = 0; nt < 4; nt++) {
      #pragma unroll
      for (int r = 0; r < 4; r++) {
        int row_l = wm*64 + mt*16 + quad*4 + r;
        int col_l = wn*64 + nt*16 + l16;
        int grow = m0 + row_l, gcol = n0 + col_l;
        float val = acc[mt][nt][r];
        if (MODE == 0) {
          OB[(size_t)grow * N + gcol] = f2bf(val);
        } else if (MODE == 1) {
          C[(size_t)grow * H_DIM + gcol] = val + resid[(size_t)grow * H_DIM + gcol];
        } else {
          if (grow < ne) {
            int tk = list[e * T_TOK + grow];
            int j  = (e == 8) ? 2 : (int)jsl[e * T_TOK + grow];
            OB[((size_t)tk * 3 + j) * H_DIM + gcol] = f2bf(val);
          }
        }
      }
    }
  }
}

// ---------------------------------------------------------------------------
// Combine: out[t] += buf[t][0] + buf[t][1] + buf[t][2]  (bf16 contributions).
// ---------------------------------------------------------------------------
__global__ __launch_bounds__(256) void combine_k(const __bf16* __restrict__ buf,
                                                 float* __restrict__ out) {
  int t = blockIdx.x, tid = threadIdx.x;
  const __bf16* base = buf + (size_t)t * 3 * H_DIM;
  bf16x8 v0 = *(const bf16x8*)(base + tid * 8);
  bf16x8 v1 = *(const bf16x8*)(base + H_DIM + tid * 8);
  bf16x8 v2 = *(const bf16x8*)(base + 2 * H_DIM + tid * 8);
  float* o = out + (size_t)t * H_DIM + tid * 8;
  float4 a = *(float4*)o, b = *(float4*)(o + 4);
  a.x += (float)v0[0] + (float)v1[0] + (float)v2[0];
  a.y += (float)v0[1] + (float)v1[1] + (float)v2[1];
  a.z += (float)v0[2] + (float)v1[2] + (float)v2[2];
  a.w += (float)v0[3] + (float)v1[3] + (float)v2[3];
  b.x += (float)v0[4] + (float)v1[4] + (float)v2[4];
  b.y += (float)v0[5] + (float)v1[5] + (float)v2[5];
  b.z += (float)v0[6] + (float)v1[6] + (float)v2[6];
  b.w += (float)v0[7] + (float)v1[7] + (float)v2[7];
  *(float4*)o = a; *(float4*)(o + 4) = b;
}

// ---------------------------------------------------------------------------
// Per (token, head): q/k RMSNorm (HD=128) + RoPE, v passthrough; bf16 in/out.
// 256-thread blocks = 4 heads; wave handles one head, lane d holds d, d+64.
// ---------------------------------------------------------------------------
__global__ __launch_bounds__(256) void rope_k(
    const __bf16* __restrict__ qkv, const float* __restrict__ qlw,
    const float* __restrict__ klw, const float* __restrict__ cosp,
    const float* __restrict__ sinp, __bf16* __restrict__ qb,
    __bf16* __restrict__ kb, __bf16* __restrict__ vb) {
  int bid = blockIdx.x;                 // T_TOK * 6
  int t = bid / 6;
  int head = (bid % 6) * 4 + (threadIdx.x >> 6);
  int b = t >> 10, s = t & 1023;
  int d = threadIdx.x & 63;
  const __bf16* src = qkv + (size_t)t * QKV_O + head * HD;
  float x1 = (float)src[d], x2 = (float)src[d + 64];
  if (head < 20) {
    float ssq = x1*x1 + x2*x2;
    #pragma unroll
    for (int m = 1; m <= 32; m <<= 1) ssq += __shfl_xor(ssq, m, 64);
    float sc = rsqrtf(ssq * (1.f / HD) + EPS);
    const float* w = (head < 16) ? qlw : klw;
    x1 = x1 * sc * w[d];
    x2 = x2 * sc * w[d + 64];
    size_t cb = (size_t)t * HD;
    float c1 = cosp[cb + d], s1 = sinp[cb + d];
    float c2 = cosp[cb + d + 64], s2 = sinp[cb + d + 64];
    float o1 = x1 * c1 - x2 * s1;
    float o2 = x2 * c2 + x1 * s2;
    if (head < 16) {
      __bf16* dst = qb + (((size_t)(b * NH + head)) * S_LEN + s) * HD;
      dst[d] = f2bf(o1); dst[d + 64] = f2bf(o2);
    } else {
      int kv = head - 16;
      __bf16* dst = kb + (((size_t)(b * NKV + kv)) * S_LEN + s) * HD;
      dst[d] = f2bf(o1); dst[d + 64] = f2bf(o2);
    }
  } else {
    int kv = head - 20;
    __bf16* dst = vb + (((size_t)(b * NKV + kv)) * S_LEN + s) * HD;
    dst[d] = src[d]; dst[d + 64] = src[d + 64];
  }
}

// ---------------------------------------------------------------------------
// V transpose: vb [g][s][d] -> vt [g][d][s]  (g = b*NKV+kv), 64x64 tiles.
// ---------------------------------------------------------------------------
__global__ __launch_bounds__(256) void vtrans_k(const __bf16* __restrict__ vb,
                                                __bf16* __restrict__ vt) {
  int s0 = blockIdx.x * 64, d0 = blockIdx.y * 64, g = blockIdx.z;
  __shared__ __bf16 sT[64 * 80];
  int tid = threadIdx.x;
  const __bf16* src = vb + (size_t)g * S_LEN * HD;
  #pragma unroll
  for (int i = 0; i < 2; i++) {
    int p = tid + 256 * i;
    int rs = p >> 3, cc = p & 7;
    bf16x8 v = *(const bf16x8*)(src + (size_t)(s0 + rs) * HD + d0 + cc * 8);
    #pragma unroll
    for (int j = 0; j < 8; j++) sT[(cc * 8 + j) * 80 + rs] = v[j];
  }
  __syncthreads();
  __bf16* dst = vt + (size_t)g * HD * S_LEN;
  #pragma unroll
  for (int i = 0; i < 2; i++) {
    int p = tid + 256 * i;
    int rd = p >> 3, cs = p & 7;
    bf16x8 v = *(const bf16x8*)&sT[rd * 80 + cs * 8];
    *(bf16x8*)(dst + (size_t)(d0 + rd) * S_LEN + s0 + cs * 8) = v;
  }
}

// ---------------------------------------------------------------------------
// Flash attention v2. 64-row Q tile, 64-col K/V tiles, global_load_lds
// staging with XOR swizzle, Vt pre-transposed globally, sP unioned onto sK.
// LDS = 48KB -> 3 blocks/CU.
// ---------------------------------------------------------------------------
__global__ __launch_bounds__(256) void flash_k(
    const __bf16* __restrict__ qb, const __bf16* __restrict__ kb,
    const __bf16* __restrict__ vt, __bf16* __restrict__ outb) {
  int qt = blockIdx.x, bh = blockIdx.y;
  int b = bh >> 4, h = bh & 15, kv = h >> 2;
  int tid = threadIdx.x, lane = tid & 63, wid = tid >> 6;
  int quad = lane >> 4, l16 = lane & 15;
  __shared__ __bf16 sQ[64 * 128];
  __shared__ __bf16 sKP[64 * 128];      // sK; reused as sP (64*72) after (c)
  __shared__ __bf16 sVt[128 * 64];
  __bf16* sK = sKP;
  __bf16* sP = sKP;

  const __bf16* qsrc = qb + (((size_t)(b * NH + h)) * S_LEN + qt * 64) * HD;
  #pragma unroll
  for (int i = 0; i < 4; i++) {
    int p = tid + 256 * i;
    int row = p >> 4, sc = p & 15, gc = sc ^ (row & 7);
    gld16(qsrc + (size_t)row * HD + gc * 8, &sQ[p * 8]);
  }
  const __bf16* kbase  = kb + ((size_t)(b * NKV + kv)) * S_LEN * HD;
  const __bf16* vtbase = vt + ((size_t)(b * NKV + kv)) * HD * S_LEN;
  const __bf16* gK[4]; const __bf16* gV[4];
  #pragma unroll
  for (int i = 0; i < 4; i++) {
    int p = tid + 256 * i;
    int rowk = p >> 4, sck = p & 15, gck = sck ^ (rowk & 7);
    gK[i] = kbase + (size_t)rowk * HD + gck * 8;
    int rowv = p >> 3, scv = p & 7, gcv = scv ^ (rowv & 7);
    gV[i] = vtbase + (size_t)rowv * S_LEN + gcv * 8;
  }
  float mrow[4], lrow[4];
  #pragma unroll
  for (int r = 0; r < 4; r++) { mrow[r] = -__builtin_inff(); lrow[r] = 0.f; }
  f32x4 accO[8];
  #pragma unroll
  for (int i = 0; i < 8; i++) accO[i] = fzero4();

  for (int kt = 0; kt < 16; kt++) {
    __syncthreads();                         // (a) prev PV done (also Q drain)
    #pragma unroll
    for (int i = 0; i < 4; i++) {
      gld16(gK[i] + (size_t)kt * 64 * HD, &sK[(tid + 256 * i) * 8]);
      gld16(gV[i] + kt * 64, &sVt[(tid + 256 * i) * 8]);
    }
    __syncthreads();                         // (b) staging visible
    f32x4 accS[4];
    #pragma unroll
    for (int jt = 0; jt < 4; jt++) accS[jt] = fzero4();
    int rowA = wid * 16 + l16;
    #pragma unroll
    for (int ks2 = 0; ks2 < 4; ks2++) {
      int posA = rowA * 16 + ((ks2 * 4 + quad) ^ (rowA & 7));
      bf16x8 aF = *(const bf16x8*)&sQ[posA * 8];
      #pragma unroll
      for (int jt = 0; jt < 4; jt++) {
        int rowB = jt * 16 + l16;
        int posB = rowB * 16 + ((ks2 * 4 + quad) ^ (rowB & 7));
        bf16x8 bF = *(const bf16x8*)&sK[posB * 8];
        accS[jt] = __builtin_amdgcn_mfma_f32_16x16x32_bf16(aF, bF, accS[jt], 0, 0, 0);
      }
    }
    float alpha[4];
    #pragma unroll
    for (int r = 0; r < 4; r++) {
      float mx = -__builtin_inff();
      #pragma unroll
      for (int jt = 0; jt < 4; jt++) {
        accS[jt][r] *= ATT_SCALE;
        mx = fmaxf(mx, accS[jt][r]);
      }
      #pragma unroll
      for (int m = 1; m <= 8; m <<= 1) mx = fmaxf(mx, __shfl_xor(mx, m, 64));
      float mn = fmaxf(mrow[r], mx);
      float al = __expf(mrow[r] - mn);
      float rs = 0.f;
      #pragma unroll
      for (int jt = 0; jt < 4; jt++) {
        float p = __expf(accS[jt][r] - mn);
        accS[jt][r] = p;
        rs += p;
      }
      #pragma unroll
      for (int m = 1; m <= 8; m <<= 1) rs += __shfl_xor(rs, m, 64);
      lrow[r] = lrow[r] * al + rs;
      mrow[r] = mn;
      alpha[r] = al;
    }
    #pragma unroll
    for (int nt = 0; nt < 8; nt++)
      #pragma unroll
      for (int r = 0; r < 4; r++) accO[nt][r] *= alpha[r];
    __syncthreads();                         // (c) all waves done reading sK
    #pragma unroll
    for (int jt = 0; jt < 4; jt++)
      #pragma unroll
      for (int r = 0; r < 4; r++)
        sP[(wid * 16 + quad * 4 + r) * 72 + jt * 16 + l16] = f2bf(accS[jt][r]);
    __syncthreads();                         // (d) sP visible
    #pragma unroll
    for (int ks2 = 0; ks2 < 2; ks2++) {
      bf16x8 aF = *(const bf16x8*)&sP[(wid * 16 + l16) * 72 + ks2 * 32 + quad * 8];
      #pragma unroll
      for (int nt = 0; nt < 8; nt++) {
        int rowB = nt * 16 + l16;
        int posB = rowB * 8 + ((ks2 * 4 + quad) ^ (rowB & 7));
        bf16x8 bF = *(const bf16x8*)&sVt[posB * 8];
        accO[nt] = __builtin_amdgcn_mfma_f32_16x16x32_bf16(aF, bF, accO[nt], 0, 0, 0);
      }
    }
  }
  #pragma unroll
  for (int nt = 0; nt < 8; nt++) {
    #pragma unroll
    for (int r = 0; r < 4; r++) {
      int srow = qt * 64 + wid * 16 + quad * 4 + r;
      float val = accO[nt][r] / lrow[r];
      outb[((size_t)(b * S_LEN + srow)) * H_DIM + h * HD + nt * 16 + l16] = f2bf(val);
    }
  }
}

// ---------------------------------------------------------------------------
// Router: also records jsl (which of the token's 2 contribution slots).
// ---------------------------------------------------------------------------
__global__ __launch_bounds__(64) void router_k(
    const float* __restrict__ hid, const float* __restrict__ ln2w,
    const float* __restrict__ gw, const float* __restrict__ gb,
    int* __restrict__ cnt, int* __restrict__ list, float* __restrict__ wsl,
    signed char* __restrict__ jsl) {
  int t = blockIdx.x;
  int lane = threadIdx.x;
  const float* xr = hid + (size_t)t * H_DIM;
  float x[32];
  float ss = 0.f;
  #pragma unroll
  for (int j = 0; j < 32; j++) { x[j] = xr[j * 64 + lane]; ss += x[j] * x[j]; }
  #pragma unroll
  for (int m = 1; m <= 32; m <<= 1) ss += __shfl_xor(ss, m, 64);
  float sc = rsqrtf(ss * (1.f / H_DIM) + EPS);
  float xn[32];
  #pragma unroll
  for (int j = 0; j < 32; j++) xn[j] = x[j] * sc * ln2w[j * 64 + lane];
  float lg[8];
  #pragma unroll
  for (int e = 0; e < 8; e++) {
    float d = 0.f;
    #pragma unroll
    for (int j = 0; j < 32; j++) d += xn[j] * gw[(size_t)e * H_DIM + j * 64 + lane];
    #pragma unroll
    for (int m = 1; m <= 32; m <<= 1) d += __shfl_xor(d, m, 64);
    lg[e] = d;
  }
  float s[8], sb[8];
  #pragma unroll
  for (int e = 0; e < 8; e++) {
    s[e] = 1.f / (1.f + __expf(-lg[e]));
    sb[e] = s[e] + gb[e];
  }
  float gs[4];
  #pragma unroll
  for (int g = 0; g < 4; g++) gs[g] = sb[2 * g] + sb[2 * g + 1];
  int g1 = 0;
  for (int g = 1; g < 4; g++) if (gs[g] > gs[g1]) g1 = g;
  int g2 = -1;
  for (int g = 0; g < 4; g++) if (g != g1 && (g2 < 0 || gs[g] > gs[g2])) g2 = g;
  unsigned emask = (3u << (2 * g1)) | (3u << (2 * g2));
  int e1 = -1;
  for (int e = 0; e < 8; e++) if (((emask >> e) & 1u) && (e1 < 0 || sb[e] > sb[e1])) e1 = e;
  int e2 = -1;
  for (int e = 0; e < 8; e++) if (((emask >> e) & 1u) && e != e1 && (e2 < 0 || sb[e] > sb[e2])) e2 = e;
  float w1 = s[e1], w2 = s[e2];
  float dn = w1 + w2 + 1e-20f;
  w1 /= dn; w2 /= dn;   // RSF = 1.0
  if (lane == 0) {
    int p1 = atomicAdd(&cnt[e1], 1);
    list[e1 * T_TOK + p1] = t; wsl[e1 * T_TOK + p1] = w1; jsl[e1 * T_TOK + p1] = 0;
    int p2 = atomicAdd(&cnt[e2], 1);
    list[e2 * T_TOK + p2] = t; wsl[e2 * T_TOK + p2] = w2; jsl[e2 * T_TOK + p2] = 1;
    list[8 * T_TOK + t] = t; wsl[8 * T_TOK + t] = 1.f;   // shared expert
  }
}

// ---------------------------------------------------------------------------
// Gathered gate+up GEMM with fused silu-mul, routing-weight fold, dbuf LDS.
// Tile 128(M) x 64(N), BK=64; wave w owns rows [32w, 32w+32).
// ---------------------------------------------------------------------------
__global__ __launch_bounds__(256) void gemm_gateup(
    const __bf16* __restrict__ X, const __bf16* __restrict__ weg,
    const __bf16* __restrict__ weu, const __bf16* __restrict__ wsg,
    const __bf16* __restrict__ wsu, const int* __restrict__ list,
    const float* __restrict__ wsl, const int* __restrict__ cnt,
    __bf16* __restrict__ he) {
  int e = blockIdx.z;
  int ne = (e == 8) ? T_TOK : cnt[e];
  int m0 = blockIdx.y * 128;
  if (m0 >= ne) return;
  int n0 = blockIdx.x * 64;
  const __bf16* bg = (e < 8) ? weg + (size_t)e * MM * H_DIM : wsg;
  const __bf16* bu = (e < 8) ? weu + (size_t)e * MM * H_DIM : wsu;
  const int* lst = list + e * T_TOK;
  __shared__ __bf16 sA[2][128 * 64];
  __shared__ __bf16 sBg[2][64 * 64];
  __shared__ __bf16 sBu[2][64 * 64];
  int tid = threadIdx.x, lane = tid & 63, wid = tid >> 6;
  int quad = lane >> 4, l16 = lane & 15;

  const __bf16* gA[4]; const __bf16* gBg[2]; const __bf16* gBu[2];
  #pragma unroll
  for (int i = 0; i < 4; i++) {
    int p = tid + 256 * i;
    int row = p >> 3, sc = p & 7, gc = sc ^ (row & 7);
    int r = m0 + row; if (r >= ne) r = ne - 1;
    int tk = lst[r];
    gA[i] = X + (size_t)tk * H_DIM + gc * 8;
  }
  #pragma unroll
  for (int i = 0; i < 2; i++) {
    int p = tid + 256 * i;
    int row = p >> 3, sc = p & 7, gc = sc ^ (row & 7);
    gBg[i] = bg + (size_t)(n0 + row) * H_DIM + gc * 8;
    gBu[i] = bu + (size_t)(n0 + row) * H_DIM + gc * 8;
  }
  f32x4 ag[2][4], au[2][4];
  #pragma unroll
  for (int i = 0; i < 2; i++)
    #pragma unroll
    for (int j = 0; j < 4; j++) { ag[i][j] = fzero4(); au[i][j] = fzero4(); }

  auto stage = [&](int buf, int k0) {
    #pragma unroll
    for (int i = 0; i < 4; i++)
      gld16(gA[i] + k0, &sA[buf][(tid + 256 * i) * 8]);
    #pragma unroll
    for (int i = 0; i < 2; i++) {
      gld16(gBg[i] + k0, &sBg[buf][(tid + 256 * i) * 8]);
      gld16(gBu[i] + k0, &sBu[buf][(tid + 256 * i) * 8]);
    }
  };
  stage(0, 0);
  int cur = 0;
  for (int k0 = 0; k0 < H_DIM; k0 += 64) {
    __syncthreads();
    if (k0 + 64 < H_DIM) stage(cur ^ 1, k0 + 64);
    #pragma unroll
    for (int ks = 0; ks < 64; ks += 32) {
      int cb = ks >> 3;
      bf16x8 aF[2], gF[4], uF[4];
      #pragma unroll
      for (int mt = 0; mt < 2; mt++) {
        int row = wid * 32 + mt * 16 + l16;
        int pos = row * 8 + ((cb + quad) ^ (row & 7));
        aF[mt] = *(const bf16x8*)&sA[cur][pos * 8];
      }
      #pragma unroll
      for (int nt = 0; nt < 4; nt++) {
        int row = nt * 16 + l16;
        int pos = row * 8 + ((cb + quad) ^ (row & 7));
        gF[nt] = *(const bf16x8*)&sBg[cur][pos * 8];
        uF[nt] = *(const bf16x8*)&sBu[cur][pos * 8];
      }
      #pragma unroll
      for (int mt = 0; mt < 2; mt++)
        #pragma unroll
        for (int nt = 0; nt < 4; nt++) {
          ag[mt][nt] = __builtin_amdgcn_mfma_f32_16x16x32_bf16(aF[mt], gF[nt], ag[mt][nt], 0, 0, 0);
          au[mt][nt] = __builtin_amdgcn_mfma_f32_16x16x32_bf16(aF[mt], uF[nt], au[mt][nt], 0, 0, 0);
        }
    }
    cur ^= 1;
  }
  #pragma unroll
  for (int mt = 0; mt < 2; mt++) {
    #pragma unroll
    for (int nt = 0; nt < 4; nt++) {
      #pragma unroll
      for (int r = 0; r < 4; r++) {
        int row_l = wid * 32 + mt * 16 + quad * 4 + r;
        int grow = m0 + row_l;
        if (grow < ne) {
          float g = ag[mt][nt][r], u = au[mt][nt][r];
          float hv = g / (1.f + __expf(-g)) * u;     // silu(g)*u
          hv *= wsl[e * T_TOK + grow];               // fold routing weight
          he[((size_t)e * T_TOK + grow) * MM + n0 + nt * 16 + l16] = f2bf(hv);
        }
      }
    }
  }
}

// ---------------------------------------------------------------------------
extern "C" void kernel_launch(void* const* d_in, const int* in_sizes, int n_in,
                              void* d_out, int out_size, void* d_ws, size_t ws_size,
                              hipStream_t stream) {
  (void)in_sizes; (void)n_in; (void)out_size; (void)ws_size;
  const float* hs     = (const float*)d_in[0];
  const float* cosp   = (const float*)d_in[1];
  const float* sinp   = (const float*)d_in[2];
  const float* ln1w   = (const float*)d_in[3];
  const float* wqkv   = (const float*)d_in[4];
  const float* qlw    = (const float*)d_in[5];
  const float* klw    = (const float*)d_in[6];
  const float* wdense = (const float*)d_in[7];
  const float* ln2w   = (const float*)d_in[8];
  const float* gw     = (const float*)d_in[9];
  const float* gbias  = (const float*)d_in[10];
  const float* weg    = (const float*)d_in[11];
  const float* weu    = (const float*)d_in[12];
  const float* wed    = (const float*)d_in[13];
  const float* wsg    = (const float*)d_in[14];
  const float* wsu    = (const float*)d_in[15];
  const float* wsd    = (const float*)d_in[16];
  float* out = (float*)d_out;

  char* ws = (char*)d_ws;
  size_t off = 0;
  auto alloc = [&](size_t b) { char* p = ws + off; off += (b + 255) & ~(size_t)255; return p; };
  __bf16* wbf   = (__bf16*)alloc((size_t)38797312 * 2);               // 74 MB
  __bf16* xb1   = (__bf16*)alloc((size_t)T_TOK * H_DIM * 2);
  __bf16* qreg  = (__bf16*)alloc((size_t)T_TOK * 3 * H_DIM * 2);      // qkv bf16 / buf
  __bf16* qb    = (__bf16*)alloc((size_t)2 * NH  * S_LEN * HD * 2);   // he span start
  __bf16* kb    = (__bf16*)alloc((size_t)2 * NKV * S_LEN * HD * 2);
  __bf16* vb    = (__bf16*)alloc((size_t)2 * NKV * S_LEN * HD * 2);
  __bf16* vt    = (__bf16*)alloc((size_t)2 * NKV * S_LEN * HD * 2);
  __bf16* outb  = (__bf16*)alloc((size_t)T_TOK * H_DIM * 2);
  __bf16* xb2   = (__bf16*)alloc((size_t)T_TOK * H_DIM * 2);
  int*    cnt   = (int*)   alloc(256);
  int*    list  = (int*)   alloc((size_t)9 * T_TOK * 4);
  float*  wsl   = (float*) alloc((size_t)9 * T_TOK * 4);
  signed char* jsl = (signed char*)alloc((size_t)9 * T_TOK);
  __bf16* qkvb  = qreg;            // [T, 3072] bf16 (dead after rope)
  __bf16* buf   = qreg;            // [T][3][H] bf16 contribs (exact same size)
  __bf16* he    = qb;              // 18.9 MB over dead qb..outb span (23 MB)

  const __bf16* wqkv_bf   = wbf;
  const __bf16* wdense_bf = wbf + 6291456;
  const __bf16* weg_bf    = wbf + 10485760;
  const __bf16* weu_bf    = wbf + 18874368;
  const __bf16* wed_bf    = wbf + 27262976;
  const __bf16* wsg_bf    = wbf + 35651584;
  const __bf16* wsu_bf    = wbf + 36700160;
  const __bf16* wsd_bf    = wbf + 37748736;

  hipMemsetAsync(cnt, 0, 256, stream);
  // 0) weights fp32 -> bf16
  wconv_k<<<18944, 256, 0, stream>>>(wqkv, wdense, weg, weu, wed, wsg, wsu, wsd, wbf);
  // 1) x = rmsnorm(hidden, ln1_w) -> bf16
  rmsnorm_k<<<T_TOK, 256, 0, stream>>>(hs, ln1w, xb1);
  // 2) qkv = x @ w_qkv^T (bf16 out)
  gemm_nt<0><<<dim3(QKV_O / 128, T_TOK / 128), 256, 0, stream>>>(
      xb1, wqkv_bf, nullptr, nullptr, qkvb, nullptr, nullptr, nullptr, nullptr, QKV_O, H_DIM);
  // 3) q/k norm + rope, v -> bf16 (b,h,s,d)
  rope_k<<<T_TOK * 6, 256, 0, stream>>>(qkvb, qlw, klw, cosp, sinp, qb, kb, vb);
  // 3b) vt = transpose(vb): [g][d][s]
  vtrans_k<<<dim3(16, 2, 8), 256, 0, stream>>>(vb, vt);
  // 4) flash attention -> outb bf16 (t, nh*hd)
  flash_k<<<dim3(S_LEN / 64, 2 * NH), 256, 0, stream>>>(qb, kb, vt, outb);
  // 5) hidden = hs + outb @ w_dense^T -> d_out (fp32)
  gemm_nt<1><<<dim3(H_DIM / 128, T_TOK / 128), 256, 0, stream>>>(
      outb, wdense_bf, nullptr, out, nullptr, hs, nullptr, nullptr, nullptr, H_DIM, H_DIM);
  // 6) x2 = rmsnorm(hidden, ln2_w) -> bf16
  rmsnorm_k<<<T_TOK, 256, 0, stream>>>(out, ln2w, xb2);
  // 7) router (writes list/wsl/jsl)
  router_k<<<T_TOK, 64, 0, stream>>>(out, ln2w, gw, gbias, cnt, list, wsl, jsl);
  // 8) gathered gate/up + silu-mul + weight fold -> he bf16
  gemm_gateup<<<dim3(MM / 64, T_TOK / 128, 9), 256, 0, stream>>>(
      xb2, weg_bf, weu_bf, wsg_bf, wsu_bf, list, wsl, cnt, he);
  // 9) down-proj -> buf[t][j][:] (conflict-free bf16 stores, no atomics)
  gemm_nt<2><<<dim3(H_DIM / 128, T_TOK / 128, 9), 256, 0, stream>>>(
      he, wed_bf, wsd_bf, nullptr, buf, nullptr, list, jsl, cnt, H_DIM, MM);
  // 10) out[t] += buf[t][0] + buf[t][1] + buf[t][2]
  combine_k<<<T_TOK, 256, 0, stream>>>(buf, out);
}

// Round 5
// 499.413 us; speedup vs baseline: 1.2558x; 1.0543x over previous
//
#include <hip/hip_runtime.h>
#include <cstdint>
#include <cstddef>

#define T_TOK 2048
#define H_DIM 2048
#define S_LEN 1024
#define HD 128
#define NH 16
#define NKV 4
#define QKV_O 3072
#define MM 512
#define EPS 1e-6f
#define ATT_SCALE 0.08838834764831845f  // 128^-0.5

typedef __bf16 bf16x8 __attribute__((ext_vector_type(8)));
typedef __bf16 bf16x4 __attribute__((ext_vector_type(4)));
typedef float  f32x4  __attribute__((ext_vector_type(4)));

__device__ __forceinline__ __bf16 f2bf(float f) {
  unsigned u = __builtin_bit_cast(unsigned, f);
  u += 0x7fffu + ((u >> 16) & 1u);           // RNE; inputs are finite
  unsigned short h = (unsigned short)(u >> 16);
  return __builtin_bit_cast(__bf16, h);
}
__device__ __forceinline__ f32x4 fzero4() {
  f32x4 z; z[0] = 0.f; z[1] = 0.f; z[2] = 0.f; z[3] = 0.f; return z;
}
// async global->LDS, 16B per lane.
__device__ __forceinline__ void gld16(const __bf16* g, __bf16* l) {
  __builtin_amdgcn_global_load_lds(
      (const __attribute__((address_space(1))) unsigned int*)g,
      (__attribute__((address_space(3))) unsigned int*)l, 16, 0, 0);
}

// ---------------------------------------------------------------------------
// Weight fp32 -> bf16 conversion. 16 elements/thread (64B read, 32B write).
// All tensor boundaries are multiples of 16, so a thread never straddles.
// ---------------------------------------------------------------------------
__global__ __launch_bounds__(256) void wconv_k(
    const float* __restrict__ s0, const float* __restrict__ s1,
    const float* __restrict__ s2, const float* __restrict__ s3,
    const float* __restrict__ s4, const float* __restrict__ s5,
    const float* __restrict__ s6, const float* __restrict__ s7,
    __bf16* __restrict__ dst) {
  size_t e = ((size_t)blockIdx.x * 256 + threadIdx.x) * 16;
  const size_t E0 = 6291456, E1 = 10485760, E2 = 18874368, E3 = 27262976,
               E4 = 35651584, E5 = 36700160, E6 = 37748736;
  const float* src; size_t base;
  if      (e < E0) { src = s0; base = 0;  }
  else if (e < E1) { src = s1; base = E0; }
  else if (e < E2) { src = s2; base = E1; }
  else if (e < E3) { src = s3; base = E2; }
  else if (e < E4) { src = s4; base = E3; }
  else if (e < E5) { src = s5; base = E4; }
  else if (e < E6) { src = s6; base = E5; }
  else             { src = s7; base = E6; }
  const float4* sp = (const float4*)(src + (e - base));
  float4 f0 = sp[0], f1 = sp[1], f2 = sp[2], f3 = sp[3];
  bf16x8 o0, o1;
  o0[0] = f2bf(f0.x); o0[1] = f2bf(f0.y); o0[2] = f2bf(f0.z); o0[3] = f2bf(f0.w);
  o0[4] = f2bf(f1.x); o0[5] = f2bf(f1.y); o0[6] = f2bf(f1.z); o0[7] = f2bf(f1.w);
  o1[0] = f2bf(f2.x); o1[1] = f2bf(f2.y); o1[2] = f2bf(f2.z); o1[3] = f2bf(f2.w);
  o1[4] = f2bf(f3.x); o1[5] = f2bf(f3.y); o1[6] = f2bf(f3.z); o1[7] = f2bf(f3.w);
  *(bf16x8*)(dst + e) = o0;
  *(bf16x8*)(dst + e + 8) = o1;
}

// ---------------------------------------------------------------------------
// RMSNorm over H=2048, fp32 in -> bf16 out. One block (256 thr) per token.
// ---------------------------------------------------------------------------
__global__ __launch_bounds__(256) void rmsnorm_k(const float* __restrict__ X,
                                                 const float* __restrict__ W,
                                                 __bf16* __restrict__ Y) {
  int t = blockIdx.x;
  int tid = threadIdx.x, lane = tid & 63, wid = tid >> 6;
  const float4* row = (const float4*)(X + (size_t)t * H_DIM);
  float4 v0 = row[tid], v1 = row[tid + 256];
  float ss = v0.x*v0.x + v0.y*v0.y + v0.z*v0.z + v0.w*v0.w
           + v1.x*v1.x + v1.y*v1.y + v1.z*v1.z + v1.w*v1.w;
  #pragma unroll
  for (int m = 1; m <= 32; m <<= 1) ss += __shfl_xor(ss, m, 64);
  __shared__ float red[4];
  if (lane == 0) red[wid] = ss;
  __syncthreads();
  float tot = red[0] + red[1] + red[2] + red[3];
  float sc = rsqrtf(tot * (1.f / H_DIM) + EPS);
  const float4* wp = (const float4*)W;
  float4 w0 = wp[tid], w1 = wp[tid + 256];
  bf16x4 o;
  o[0] = f2bf(v0.x*w0.x*sc); o[1] = f2bf(v0.y*w0.y*sc);
  o[2] = f2bf(v0.z*w0.z*sc); o[3] = f2bf(v0.w*w0.w*sc);
  *(bf16x4*)&Y[(size_t)t*H_DIM + tid*4] = o;
  o[0] = f2bf(v1.x*w1.x*sc); o[1] = f2bf(v1.y*w1.y*sc);
  o[2] = f2bf(v1.z*w1.z*sc); o[3] = f2bf(v1.w*w1.w*sc);
  *(bf16x4*)&Y[(size_t)t*H_DIM + 1024 + tid*4] = o;
}

// ---------------------------------------------------------------------------
// NT GEMM, 64(M) x 128(N) tile, BK=64, dbuf LDS, m97-style staging.
// 4 waves in 2x2: wave (wm,wn) owns rows [32wm,32wm+32) x cols [64wn,64wn+64).
// Grid: qkv 768 blocks (3/CU), dense 512 (2/CU) -- fixes 1-block/CU starvation.
// MODE 0: OB bf16 plain store (ld N)            [qkv]
// MODE 1: C fp32 = acc + resid (ld 2048)        [dense + residual]
// ---------------------------------------------------------------------------
template<int MODE>
__global__ __launch_bounds__(256) void gemm64_nt(
    const __bf16* __restrict__ A, const __bf16* __restrict__ B,
    float* __restrict__ C, __bf16* __restrict__ OB,
    const float* __restrict__ resid, int N, int K) {
  int m0 = blockIdx.y * 64;
  int n0 = blockIdx.x * 128;
  __shared__ __bf16 sA[2][64 * 64];
  __shared__ __bf16 sB[2][128 * 64];
  int tid = threadIdx.x, lane = tid & 63, wid = tid >> 6;
  int quad = lane >> 4, l16 = lane & 15;
  int wm = wid & 1, wn = wid >> 1;

  const __bf16* gA[2]; const __bf16* gB[4];
  #pragma unroll
  for (int i = 0; i < 2; i++) {
    int p = tid + 256 * i;
    int row = p >> 3, sc = p & 7, gc = sc ^ (row & 7);
    gA[i] = A + (size_t)(m0 + row) * K + gc * 8;
  }
  #pragma unroll
  for (int i = 0; i < 4; i++) {
    int p = tid + 256 * i;
    int row = p >> 3, sc = p & 7, gc = sc ^ (row & 7);
    gB[i] = B + (size_t)(n0 + row) * K + gc * 8;
  }
  f32x4 acc[2][4];
  #pragma unroll
  for (int i = 0; i < 2; i++)
    #pragma unroll
    for (int j = 0; j < 4; j++) acc[i][j] = fzero4();

  auto stage = [&](int buf, int k0) {
    #pragma unroll
    for (int i = 0; i < 2; i++)
      gld16(gA[i] + k0, &sA[buf][(tid + 256 * i) * 8]);
    #pragma unroll
    for (int i = 0; i < 4; i++)
      gld16(gB[i] + k0, &sB[buf][(tid + 256 * i) * 8]);
  };
  stage(0, 0);
  int cur = 0;
  for (int k0 = 0; k0 < K; k0 += 64) {
    __syncthreads();
    if (k0 + 64 < K) stage(cur ^ 1, k0 + 64);
    #pragma unroll
    for (int ks = 0; ks < 64; ks += 32) {
      int cb = ks >> 3;
      bf16x8 aF[2], bF[4];
      #pragma unroll
      for (int mt = 0; mt < 2; mt++) {
        int row = wm * 32 + mt * 16 + l16;
        int pos = row * 8 + ((cb + quad) ^ (row & 7));
        aF[mt] = *(const bf16x8*)&sA[cur][pos * 8];
      }
      #pragma unroll
      for (int nt = 0; nt < 4; nt++) {
        int row = wn * 64 + nt * 16 + l16;
        int pos = row * 8 + ((cb + quad) ^ (row & 7));
        bF[nt] = *(const bf16x8*)&sB[cur][pos * 8];
      }
      #pragma unroll
      for (int mt = 0; mt < 2; mt++)
        #pragma unroll
        for (int nt = 0; nt < 4; nt++)
          acc[mt][nt] = __builtin_amdgcn_mfma_f32_16x16x32_bf16(
              aF[mt], bF[nt], acc[mt][nt], 0, 0, 0);
    }
    cur ^= 1;
  }
  #pragma unroll
  for (int mt = 0; mt < 2; mt++) {
    #pragma unroll
    for (int nt = 0; nt < 4; nt++) {
      #pragma unroll
      for (int r = 0; r < 4; r++) {
        int grow = m0 + wm*32 + mt*16 + quad*4 + r;
        int gcol = n0 + wn*64 + nt*16 + l16;
        float val = acc[mt][nt][r];
        if (MODE == 0) {
          OB[(size_t)grow * N + gcol] = f2bf(val);
        } else {
          C[(size_t)grow * H_DIM + gcol] = val + resid[(size_t)grow * H_DIM + gcol];
        }
      }
    }
  }
}

// ---------------------------------------------------------------------------
// Expert down-proj GEMM (128x128 tile, dbuf). grid.z = expert (8 = shared).
// Writes buf[t][j][:] bf16 -- conflict-free scatter, no atomics.
// ---------------------------------------------------------------------------
__global__ __launch_bounds__(256) void gemm_down(
    const __bf16* __restrict__ A, const __bf16* __restrict__ B,
    const __bf16* __restrict__ B2, __bf16* __restrict__ OB,
    const int* __restrict__ list, const signed char* __restrict__ jsl,
    const int* __restrict__ cnt) {
  int e  = blockIdx.z;
  int ne = (e == 8) ? T_TOK : cnt[e];
  int m0 = blockIdx.y * 128;
  if (m0 >= ne) return;
  int n0 = blockIdx.x * 128;
  const __bf16* Ab = A + (size_t)e * T_TOK * MM;
  const __bf16* Bb = (e < 8) ? B + (size_t)e * H_DIM * MM : B2;
  const int K = MM;
  __shared__ __bf16 sA[2][128 * 64];
  __shared__ __bf16 sB[2][128 * 64];
  int tid = threadIdx.x, lane = tid & 63, wid = tid >> 6;
  int quad = lane >> 4, l16 = lane & 15;
  int wm = wid & 1, wn = wid >> 1;

  const __bf16* gA[4]; const __bf16* gB[4];
  #pragma unroll
  for (int i = 0; i < 4; i++) {
    int p = tid + 256 * i;
    int row = p >> 3, sc = p & 7, gc = sc ^ (row & 7);
    gA[i] = Ab + (size_t)(m0 + row) * K + gc * 8;
    gB[i] = Bb + (size_t)(n0 + row) * K + gc * 8;
  }
  f32x4 acc[4][4];
  #pragma unroll
  for (int i = 0; i < 4; i++)
    #pragma unroll
    for (int j = 0; j < 4; j++) acc[i][j] = fzero4();

  auto stage = [&](int buf, int k0) {
    #pragma unroll
    for (int i = 0; i < 4; i++) {
      gld16(gA[i] + k0, &sA[buf][(tid + 256 * i) * 8]);
      gld16(gB[i] + k0, &sB[buf][(tid + 256 * i) * 8]);
    }
  };
  stage(0, 0);
  int cur = 0;
  for (int k0 = 0; k0 < K; k0 += 64) {
    __syncthreads();
    if (k0 + 64 < K) stage(cur ^ 1, k0 + 64);
    #pragma unroll
    for (int ks = 0; ks < 64; ks += 32) {
      int cb = ks >> 3;
      bf16x8 aF[4], bF[4];
      #pragma unroll
      for (int mt = 0; mt < 4; mt++) {
        int row = wm * 64 + mt * 16 + l16;
        int pos = row * 8 + ((cb + quad) ^ (row & 7));
        aF[mt] = *(const bf16x8*)&sA[cur][pos * 8];
      }
      #pragma unroll
      for (int nt = 0; nt < 4; nt++) {
        int row = wn * 64 + nt * 16 + l16;
        int pos = row * 8 + ((cb + quad) ^ (row & 7));
        bF[nt] = *(const bf16x8*)&sB[cur][pos * 8];
      }
      #pragma unroll
      for (int mt = 0; mt < 4; mt++)
        #pragma unroll
        for (int nt = 0; nt < 4; nt++)
          acc[mt][nt] = __builtin_amdgcn_mfma_f32_16x16x32_bf16(
              aF[mt], bF[nt], acc[mt][nt], 0, 0, 0);
    }
    cur ^= 1;
  }
  #pragma unroll
  for (int mt = 0; mt < 4; mt++) {
    #pragma unroll
    for (int nt = 0; nt < 4; nt++) {
      #pragma unroll
      for (int r = 0; r < 4; r++) {
        int grow = m0 + wm*64 + mt*16 + quad*4 + r;
        int gcol = n0 + wn*64 + nt*16 + l16;
        if (grow < ne) {
          int tk = list[e * T_TOK + grow];
          int j  = (e == 8) ? 2 : (int)jsl[e * T_TOK + grow];
          OB[((size_t)tk * 3 + j) * H_DIM + gcol] = f2bf(acc[mt][nt][r]);
        }
      }
    }
  }
}

// ---------------------------------------------------------------------------
// Combine: out[t] += buf[t][0] + buf[t][1] + buf[t][2]  (bf16 contributions).
// ---------------------------------------------------------------------------
__global__ __launch_bounds__(256) void combine_k(const __bf16* __restrict__ buf,
                                                 float* __restrict__ out) {
  int t = blockIdx.x, tid = threadIdx.x;
  const __bf16* base = buf + (size_t)t * 3 * H_DIM;
  bf16x8 v0 = *(const bf16x8*)(base + tid * 8);
  bf16x8 v1 = *(const bf16x8*)(base + H_DIM + tid * 8);
  bf16x8 v2 = *(const bf16x8*)(base + 2 * H_DIM + tid * 8);
  float* o = out + (size_t)t * H_DIM + tid * 8;
  float4 a = *(float4*)o, b = *(float4*)(o + 4);
  a.x += (float)v0[0] + (float)v1[0] + (float)v2[0];
  a.y += (float)v0[1] + (float)v1[1] + (float)v2[1];
  a.z += (float)v0[2] + (float)v1[2] + (float)v2[2];
  a.w += (float)v0[3] + (float)v1[3] + (float)v2[3];
  b.x += (float)v0[4] + (float)v1[4] + (float)v2[4];
  b.y += (float)v0[5] + (float)v1[5] + (float)v2[5];
  b.z += (float)v0[6] + (float)v1[6] + (float)v2[6];
  b.w += (float)v0[7] + (float)v1[7] + (float)v2[7];
  *(float4*)o = a; *(float4*)(o + 4) = b;
}

// ---------------------------------------------------------------------------
// Per (token, head): q/k RMSNorm (HD=128) + RoPE, v passthrough; bf16 in/out.
// ---------------------------------------------------------------------------
__global__ __launch_bounds__(256) void rope_k(
    const __bf16* __restrict__ qkv, const float* __restrict__ qlw,
    const float* __restrict__ klw, const float* __restrict__ cosp,
    const float* __restrict__ sinp, __bf16* __restrict__ qb,
    __bf16* __restrict__ kb, __bf16* __restrict__ vb) {
  int bid = blockIdx.x;                 // T_TOK * 6
  int t = bid / 6;
  int head = (bid % 6) * 4 + (threadIdx.x >> 6);
  int b = t >> 10, s = t & 1023;
  int d = threadIdx.x & 63;
  const __bf16* src = qkv + (size_t)t * QKV_O + head * HD;
  float x1 = (float)src[d], x2 = (float)src[d + 64];
  if (head < 20) {
    float ssq = x1*x1 + x2*x2;
    #pragma unroll
    for (int m = 1; m <= 32; m <<= 1) ssq += __shfl_xor(ssq, m, 64);
    float sc = rsqrtf(ssq * (1.f / HD) + EPS);
    const float* w = (head < 16) ? qlw : klw;
    x1 = x1 * sc * w[d];
    x2 = x2 * sc * w[d + 64];
    size_t cb = (size_t)t * HD;
    float c1 = cosp[cb + d], s1 = sinp[cb + d];
    float c2 = cosp[cb + d + 64], s2 = sinp[cb + d + 64];
    float o1 = x1 * c1 - x2 * s1;
    float o2 = x2 * c2 + x1 * s2;
    if (head < 16) {
      __bf16* dst = qb + (((size_t)(b * NH + head)) * S_LEN + s) * HD;
      dst[d] = f2bf(o1); dst[d + 64] = f2bf(o2);
    } else {
      int kv = head - 16;
      __bf16* dst = kb + (((size_t)(b * NKV + kv)) * S_LEN + s) * HD;
      dst[d] = f2bf(o1); dst[d + 64] = f2bf(o2);
    }
  } else {
    int kv = head - 20;
    __bf16* dst = vb + (((size_t)(b * NKV + kv)) * S_LEN + s) * HD;
    dst[d] = src[d]; dst[d + 64] = src[d + 64];
  }
}

// ---------------------------------------------------------------------------
// V transpose: vb [g][s][d] -> vt [g][d][s]  (g = b*NKV+kv), 64x64 tiles.
// ---------------------------------------------------------------------------
__global__ __launch_bounds__(256) void vtrans_k(const __bf16* __restrict__ vb,
                                                __bf16* __restrict__ vt) {
  int s0 = blockIdx.x * 64, d0 = blockIdx.y * 64, g = blockIdx.z;
  __shared__ __bf16 sT[64 * 80];
  int tid = threadIdx.x;
  const __bf16* src = vb + (size_t)g * S_LEN * HD;
  #pragma unroll
  for (int i = 0; i < 2; i++) {
    int p = tid + 256 * i;
    int rs = p >> 3, cc = p & 7;
    bf16x8 v = *(const bf16x8*)(src + (size_t)(s0 + rs) * HD + d0 + cc * 8);
    #pragma unroll
    for (int j = 0; j < 8; j++) sT[(cc * 8 + j) * 80 + rs] = v[j];
  }
  __syncthreads();
  __bf16* dst = vt + (size_t)g * HD * S_LEN;
  #pragma unroll
  for (int i = 0; i < 2; i++) {
    int p = tid + 256 * i;
    int rd = p >> 3, cs = p & 7;
    bf16x8 v = *(const bf16x8*)&sT[rd * 80 + cs * 8];
    *(bf16x8*)(dst + (size_t)(d0 + rd) * S_LEN + s0 + cs * 8) = v;
  }
}

// ---------------------------------------------------------------------------
// Flash attention v2 (unchanged from round 3).
// ---------------------------------------------------------------------------
__global__ __launch_bounds__(256) void flash_k(
    const __bf16* __restrict__ qb, const __bf16* __restrict__ kb,
    const __bf16* __restrict__ vt, __bf16* __restrict__ outb) {
  int qt = blockIdx.x, bh = blockIdx.y;
  int b = bh >> 4, h = bh & 15, kv = h >> 2;
  int tid = threadIdx.x, lane = tid & 63, wid = tid >> 6;
  int quad = lane >> 4, l16 = lane & 15;
  __shared__ __bf16 sQ[64 * 128];
  __shared__ __bf16 sKP[64 * 128];
  __shared__ __bf16 sVt[128 * 64];
  __bf16* sK = sKP;
  __bf16* sP = sKP;

  const __bf16* qsrc = qb + (((size_t)(b * NH + h)) * S_LEN + qt * 64) * HD;
  #pragma unroll
  for (int i = 0; i < 4; i++) {
    int p = tid + 256 * i;
    int row = p >> 4, sc = p & 15, gc = sc ^ (row & 7);
    gld16(qsrc + (size_t)row * HD + gc * 8, &sQ[p * 8]);
  }
  const __bf16* kbase  = kb + ((size_t)(b * NKV + kv)) * S_LEN * HD;
  const __bf16* vtbase = vt + ((size_t)(b * NKV + kv)) * HD * S_LEN;
  const __bf16* gK[4]; const __bf16* gV[4];
  #pragma unroll
  for (int i = 0; i < 4; i++) {
    int p = tid + 256 * i;
    int rowk = p >> 4, sck = p & 15, gck = sck ^ (rowk & 7);
    gK[i] = kbase + (size_t)rowk * HD + gck * 8;
    int rowv = p >> 3, scv = p & 7, gcv = scv ^ (rowv & 7);
    gV[i] = vtbase + (size_t)rowv * S_LEN + gcv * 8;
  }
  float mrow[4], lrow[4];
  #pragma unroll
  for (int r = 0; r < 4; r++) { mrow[r] = -__builtin_inff(); lrow[r] = 0.f; }
  f32x4 accO[8];
  #pragma unroll
  for (int i = 0; i < 8; i++) accO[i] = fzero4();

  for (int kt = 0; kt < 16; kt++) {
    __syncthreads();
    #pragma unroll
    for (int i = 0; i < 4; i++) {
      gld16(gK[i] + (size_t)kt * 64 * HD, &sK[(tid + 256 * i) * 8]);
      gld16(gV[i] + kt * 64, &sVt[(tid + 256 * i) * 8]);
    }
    __syncthreads();
    f32x4 accS[4];
    #pragma unroll
    for (int jt = 0; jt < 4; jt++) accS[jt] = fzero4();
    int rowA = wid * 16 + l16;
    #pragma unroll
    for (int ks2 = 0; ks2 < 4; ks2++) {
      int posA = rowA * 16 + ((ks2 * 4 + quad) ^ (rowA & 7));
      bf16x8 aF = *(const bf16x8*)&sQ[posA * 8];
      #pragma unroll
      for (int jt = 0; jt < 4; jt++) {
        int rowB = jt * 16 + l16;
        int posB = rowB * 16 + ((ks2 * 4 + quad) ^ (rowB & 7));
        bf16x8 bF = *(const bf16x8*)&sK[posB * 8];
        accS[jt] = __builtin_amdgcn_mfma_f32_16x16x32_bf16(aF, bF, accS[jt], 0, 0, 0);
      }
    }
    float alpha[4];
    #pragma unroll
    for (int r = 0; r < 4; r++) {
      float mx = -__builtin_inff();
      #pragma unroll
      for (int jt = 0; jt < 4; jt++) {
        accS[jt][r] *= ATT_SCALE;
        mx = fmaxf(mx, accS[jt][r]);
      }
      #pragma unroll
      for (int m = 1; m <= 8; m <<= 1) mx = fmaxf(mx, __shfl_xor(mx, m, 64));
      float mn = fmaxf(mrow[r], mx);
      float al = __expf(mrow[r] - mn);
      float rs = 0.f;
      #pragma unroll
      for (int jt = 0; jt < 4; jt++) {
        float p = __expf(accS[jt][r] - mn);
        accS[jt][r] = p;
        rs += p;
      }
      #pragma unroll
      for (int m = 1; m <= 8; m <<= 1) rs += __shfl_xor(rs, m, 64);
      lrow[r] = lrow[r] * al + rs;
      mrow[r] = mn;
      alpha[r] = al;
    }
    #pragma unroll
    for (int nt = 0; nt < 8; nt++)
      #pragma unroll
      for (int r = 0; r < 4; r++) accO[nt][r] *= alpha[r];
    __syncthreads();
    #pragma unroll
    for (int jt = 0; jt < 4; jt++)
      #pragma unroll
      for (int r = 0; r < 4; r++)
        sP[(wid * 16 + quad * 4 + r) * 72 + jt * 16 + l16] = f2bf(accS[jt][r]);
    __syncthreads();
    #pragma unroll
    for (int ks2 = 0; ks2 < 2; ks2++) {
      bf16x8 aF = *(const bf16x8*)&sP[(wid * 16 + l16) * 72 + ks2 * 32 + quad * 8];
      #pragma unroll
      for (int nt = 0; nt < 8; nt++) {
        int rowB = nt * 16 + l16;
        int posB = rowB * 8 + ((ks2 * 4 + quad) ^ (rowB & 7));
        bf16x8 bF = *(const bf16x8*)&sVt[posB * 8];
        accO[nt] = __builtin_amdgcn_mfma_f32_16x16x32_bf16(aF, bF, accO[nt], 0, 0, 0);
      }
    }
  }
  #pragma unroll
  for (int nt = 0; nt < 8; nt++) {
    #pragma unroll
    for (int r = 0; r < 4; r++) {
      int srow = qt * 64 + wid * 16 + quad * 4 + r;
      float val = accO[nt][r] / lrow[r];
      outb[((size_t)(b * S_LEN + srow)) * H_DIM + h * HD + nt * 16 + l16] = f2bf(val);
    }
  }
}

// ---------------------------------------------------------------------------
// Router: records list/wsl/jsl per expert; expert 8 = shared (all tokens).
// ---------------------------------------------------------------------------
__global__ __launch_bounds__(64) void router_k(
    const float* __restrict__ hid, const float* __restrict__ ln2w,
    const float* __restrict__ gw, const float* __restrict__ gb,
    int* __restrict__ cnt, int* __restrict__ list, float* __restrict__ wsl,
    signed char* __restrict__ jsl) {
  int t = blockIdx.x;
  int lane = threadIdx.x;
  const float* xr = hid + (size_t)t * H_DIM;
  float x[32];
  float ss = 0.f;
  #pragma unroll
  for (int j = 0; j < 32; j++) { x[j] = xr[j * 64 + lane]; ss += x[j] * x[j]; }
  #pragma unroll
  for (int m = 1; m <= 32; m <<= 1) ss += __shfl_xor(ss, m, 64);
  float sc = rsqrtf(ss * (1.f / H_DIM) + EPS);
  float xn[32];
  #pragma unroll
  for (int j = 0; j < 32; j++) xn[j] = x[j] * sc * ln2w[j * 64 + lane];
  float lg[8];
  #pragma unroll
  for (int e = 0; e < 8; e++) {
    float d = 0.f;
    #pragma unroll
    for (int j = 0; j < 32; j++) d += xn[j] * gw[(size_t)e * H_DIM + j * 64 + lane];
    #pragma unroll
    for (int m = 1; m <= 32; m <<= 1) d += __shfl_xor(d, m, 64);
    lg[e] = d;
  }
  float s[8], sb[8];
  #pragma unroll
  for (int e = 0; e < 8; e++) {
    s[e] = 1.f / (1.f + __expf(-lg[e]));
    sb[e] = s[e] + gb[e];
  }
  float gs[4];
  #pragma unroll
  for (int g = 0; g < 4; g++) gs[g] = sb[2 * g] + sb[2 * g + 1];
  int g1 = 0;
  for (int g = 1; g < 4; g++) if (gs[g] > gs[g1]) g1 = g;
  int g2 = -1;
  for (int g = 0; g < 4; g++) if (g != g1 && (g2 < 0 || gs[g] > gs[g2])) g2 = g;
  unsigned emask = (3u << (2 * g1)) | (3u << (2 * g2));
  int e1 = -1;
  for (int e = 0; e < 8; e++) if (((emask >> e) & 1u) && (e1 < 0 || sb[e] > sb[e1])) e1 = e;
  int e2 = -1;
  for (int e = 0; e < 8; e++) if (((emask >> e) & 1u) && e != e1 && (e2 < 0 || sb[e] > sb[e2])) e2 = e;
  float w1 = s[e1], w2 = s[e2];
  float dn = w1 + w2 + 1e-20f;
  w1 /= dn; w2 /= dn;   // RSF = 1.0
  if (lane == 0) {
    int p1 = atomicAdd(&cnt[e1], 1);
    list[e1 * T_TOK + p1] = t; wsl[e1 * T_TOK + p1] = w1; jsl[e1 * T_TOK + p1] = 0;
    int p2 = atomicAdd(&cnt[e2], 1);
    list[e2 * T_TOK + p2] = t; wsl[e2 * T_TOK + p2] = w2; jsl[e2 * T_TOK + p2] = 1;
    list[8 * T_TOK + t] = t; wsl[8 * T_TOK + t] = 1.f;   // shared expert
  }
}

// ---------------------------------------------------------------------------
// Gathered gate+up GEMM with fused silu-mul, routing-weight fold, dbuf LDS.
// Tile 128(M) x 64(N), BK=64; wave w owns rows [32w, 32w+32).
// ---------------------------------------------------------------------------
__global__ __launch_bounds__(256) void gemm_gateup(
    const __bf16* __restrict__ X, const __bf16* __restrict__ weg,
    const __bf16* __restrict__ weu, const __bf16* __restrict__ wsg,
    const __bf16* __restrict__ wsu, const int* __restrict__ list,
    const float* __restrict__ wsl, const int* __restrict__ cnt,
    __bf16* __restrict__ he) {
  int e = blockIdx.z;
  int ne = (e == 8) ? T_TOK : cnt[e];
  int m0 = blockIdx.y * 128;
  if (m0 >= ne) return;
  int n0 = blockIdx.x * 64;
  const __bf16* bg = (e < 8) ? weg + (size_t)e * MM * H_DIM : wsg;
  const __bf16* bu = (e < 8) ? weu + (size_t)e * MM * H_DIM : wsu;
  const int* lst = list + e * T_TOK;
  __shared__ __bf16 sA[2][128 * 64];
  __shared__ __bf16 sBg[2][64 * 64];
  __shared__ __bf16 sBu[2][64 * 64];
  int tid = threadIdx.x, lane = tid & 63, wid = tid >> 6;
  int quad = lane >> 4, l16 = lane & 15;

  const __bf16* gA[4]; const __bf16* gBg[2]; const __bf16* gBu[2];
  #pragma unroll
  for (int i = 0; i < 4; i++) {
    int p = tid + 256 * i;
    int row = p >> 3, sc = p & 7, gc = sc ^ (row & 7);
    int r = m0 + row; if (r >= ne) r = ne - 1;
    int tk = lst[r];
    gA[i] = X + (size_t)tk * H_DIM + gc * 8;
  }
  #pragma unroll
  for (int i = 0; i < 2; i++) {
    int p = tid + 256 * i;
    int row = p >> 3, sc = p & 7, gc = sc ^ (row & 7);
    gBg[i] = bg + (size_t)(n0 + row) * H_DIM + gc * 8;
    gBu[i] = bu + (size_t)(n0 + row) * H_DIM + gc * 8;
  }
  f32x4 ag[2][4], au[2][4];
  #pragma unroll
  for (int i = 0; i < 2; i++)
    #pragma unroll
    for (int j = 0; j < 4; j++) { ag[i][j] = fzero4(); au[i][j] = fzero4(); }

  auto stage = [&](int buf, int k0) {
    #pragma unroll
    for (int i = 0; i < 4; i++)
      gld16(gA[i] + k0, &sA[buf][(tid + 256 * i) * 8]);
    #pragma unroll
    for (int i = 0; i < 2; i++) {
      gld16(gBg[i] + k0, &sBg[buf][(tid + 256 * i) * 8]);
      gld16(gBu[i] + k0, &sBu[buf][(tid + 256 * i) * 8]);
    }
  };
  stage(0, 0);
  int cur = 0;
  for (int k0 = 0; k0 < H_DIM; k0 += 64) {
    __syncthreads();
    if (k0 + 64 < H_DIM) stage(cur ^ 1, k0 + 64);
    #pragma unroll
    for (int ks = 0; ks < 64; ks += 32) {
      int cb = ks >> 3;
      bf16x8 aF[2], gF[4], uF[4];
      #pragma unroll
      for (int mt = 0; mt < 2; mt++) {
        int row = wid * 32 + mt * 16 + l16;
        int pos = row * 8 + ((cb + quad) ^ (row & 7));
        aF[mt] = *(const bf16x8*)&sA[cur][pos * 8];
      }
      #pragma unroll
      for (int nt = 0; nt < 4; nt++) {
        int row = nt * 16 + l16;
        int pos = row * 8 + ((cb + quad) ^ (row & 7));
        gF[nt] = *(const bf16x8*)&sBg[cur][pos * 8];
        uF[nt] = *(const bf16x8*)&sBu[cur][pos * 8];
      }
      #pragma unroll
      for (int mt = 0; mt < 2; mt++)
        #pragma unroll
        for (int nt = 0; nt < 4; nt++) {
          ag[mt][nt] = __builtin_amdgcn_mfma_f32_16x16x32_bf16(aF[mt], gF[nt], ag[mt][nt], 0, 0, 0);
          au[mt][nt] = __builtin_amdgcn_mfma_f32_16x16x32_bf16(aF[mt], uF[nt], au[mt][nt], 0, 0, 0);
        }
    }
    cur ^= 1;
  }
  #pragma unroll
  for (int mt = 0; mt < 2; mt++) {
    #pragma unroll
    for (int nt = 0; nt < 4; nt++) {
      #pragma unroll
      for (int r = 0; r < 4; r++) {
        int row_l = wid * 32 + mt * 16 + quad * 4 + r;
        int grow = m0 + row_l;
        if (grow < ne) {
          float g = ag[mt][nt][r], u = au[mt][nt][r];
          float hv = g / (1.f + __expf(-g)) * u;     // silu(g)*u
          hv *= wsl[e * T_TOK + grow];               // fold routing weight
          he[((size_t)e * T_TOK + grow) * MM + n0 + nt * 16 + l16] = f2bf(hv);
        }
      }
    }
  }
}

// ---------------------------------------------------------------------------
extern "C" void kernel_launch(void* const* d_in, const int* in_sizes, int n_in,
                              void* d_out, int out_size, void* d_ws, size_t ws_size,
                              hipStream_t stream) {
  (void)in_sizes; (void)n_in; (void)out_size; (void)ws_size;
  const float* hs     = (const float*)d_in[0];
  const float* cosp   = (const float*)d_in[1];
  const float* sinp   = (const float*)d_in[2];
  const float* ln1w   = (const float*)d_in[3];
  const float* wqkv   = (const float*)d_in[4];
  const float* qlw    = (const float*)d_in[5];
  const float* klw    = (const float*)d_in[6];
  const float* wdense = (const float*)d_in[7];
  const float* ln2w   = (const float*)d_in[8];
  const float* gw     = (const float*)d_in[9];
  const float* gbias  = (const float*)d_in[10];
  const float* weg    = (const float*)d_in[11];
  const float* weu    = (const float*)d_in[12];
  const float* wed    = (const float*)d_in[13];
  const float* wsg    = (const float*)d_in[14];
  const float* wsu    = (const float*)d_in[15];
  const float* wsd    = (const float*)d_in[16];
  float* out = (float*)d_out;

  char* ws = (char*)d_ws;
  size_t off = 0;
  auto alloc = [&](size_t b) { char* p = ws + off; off += (b + 255) & ~(size_t)255; return p; };
  __bf16* wbf   = (__bf16*)alloc((size_t)38797312 * 2);               // 74 MB
  __bf16* xb1   = (__bf16*)alloc((size_t)T_TOK * H_DIM * 2);
  __bf16* qreg  = (__bf16*)alloc((size_t)T_TOK * 3 * H_DIM * 2);      // qkv bf16 / buf
  __bf16* qb    = (__bf16*)alloc((size_t)2 * NH  * S_LEN * HD * 2);   // he span start
  __bf16* kb    = (__bf16*)alloc((size_t)2 * NKV * S_LEN * HD * 2);
  __bf16* vb    = (__bf16*)alloc((size_t)2 * NKV * S_LEN * HD * 2);
  __bf16* vt    = (__bf16*)alloc((size_t)2 * NKV * S_LEN * HD * 2);
  __bf16* outb  = (__bf16*)alloc((size_t)T_TOK * H_DIM * 2);
  __bf16* xb2   = (__bf16*)alloc((size_t)T_TOK * H_DIM * 2);
  int*    cnt   = (int*)   alloc(256);
  int*    list  = (int*)   alloc((size_t)9 * T_TOK * 4);
  float*  wsl   = (float*) alloc((size_t)9 * T_TOK * 4);
  signed char* jsl = (signed char*)alloc((size_t)9 * T_TOK);
  __bf16* qkvb  = qreg;            // [T, 3072] bf16 (dead after rope)
  __bf16* buf   = qreg;            // [T][3][H] bf16 contribs (same size)
  __bf16* he    = qb;              // 18.9 MB over dead qb..outb span (23 MB)

  const __bf16* wqkv_bf   = wbf;
  const __bf16* wdense_bf = wbf + 6291456;
  const __bf16* weg_bf    = wbf + 10485760;
  const __bf16* weu_bf    = wbf + 18874368;
  const __bf16* wed_bf    = wbf + 27262976;
  const __bf16* wsg_bf    = wbf + 35651584;
  const __bf16* wsu_bf    = wbf + 36700160;
  const __bf16* wsd_bf    = wbf + 37748736;

  hipMemsetAsync(cnt, 0, 256, stream);
  // 0) weights fp32 -> bf16 (16 elems/thread)
  wconv_k<<<9472, 256, 0, stream>>>(wqkv, wdense, weg, weu, wed, wsg, wsu, wsd, wbf);
  // 1) x = rmsnorm(hidden, ln1_w) -> bf16
  rmsnorm_k<<<T_TOK, 256, 0, stream>>>(hs, ln1w, xb1);
  // 2) qkv = x @ w_qkv^T (bf16 out), 64x128 tiles -> 768 blocks (3/CU)
  gemm64_nt<0><<<dim3(QKV_O / 128, T_TOK / 64), 256, 0, stream>>>(
      xb1, wqkv_bf, nullptr, qkvb, nullptr, QKV_O, H_DIM);
  // 3) q/k norm + rope, v -> bf16 (b,h,s,d)
  rope_k<<<T_TOK * 6, 256, 0, stream>>>(qkvb, qlw, klw, cosp, sinp, qb, kb, vb);
  // 3b) vt = transpose(vb): [g][d][s]
  vtrans_k<<<dim3(16, 2, 8), 256, 0, stream>>>(vb, vt);
  // 4) flash attention -> outb bf16 (t, nh*hd)
  flash_k<<<dim3(S_LEN / 64, 2 * NH), 256, 0, stream>>>(qb, kb, vt, outb);
  // 5) hidden = hs + outb @ w_dense^T -> d_out, 64x128 tiles -> 512 blocks
  gemm64_nt<1><<<dim3(H_DIM / 128, T_TOK / 64), 256, 0, stream>>>(
      outb, wdense_bf, out, nullptr, hs, H_DIM, H_DIM);
  // 6) x2 = rmsnorm(hidden, ln2_w) -> bf16
  rmsnorm_k<<<T_TOK, 256, 0, stream>>>(out, ln2w, xb2);
  // 7) router (writes list/wsl/jsl)
  router_k<<<T_TOK, 64, 0, stream>>>(out, ln2w, gw, gbias, cnt, list, wsl, jsl);
  // 8) gathered gate/up + silu-mul + weight fold -> he bf16
  gemm_gateup<<<dim3(MM / 64, T_TOK / 128, 9), 256, 0, stream>>>(
      xb2, weg_bf, weu_bf, wsg_bf, wsu_bf, list, wsl, cnt, he);
  // 9) down-proj -> buf[t][j][:] (conflict-free bf16 stores, no atomics)
  gemm_down<<<dim3(H_DIM / 128, T_TOK / 128, 9), 256, 0, stream>>>(
      he, wed_bf, wsd_bf, buf, list, jsl, cnt);
  // 10) out[t] += buf[t][0] + buf[t][1] + buf[t][2]
  combine_k<<<T_TOK, 256, 0, stream>>>(buf, out);
}